// Round 8
// baseline (562.056 us; speedup 1.0000x reference)
//
#include <hip/hip_runtime.h>
#include <math.h>

typedef unsigned long long u64;
typedef unsigned int u32;
typedef unsigned short u16;
typedef unsigned char u8;

#define VOL 1048576              // 64*128*128
#define NTOT 2097152             // 2 batches
#define NWORDS 32768             // NTOT/64
#define PC0 8192                 // k_init blocks / partial stride
#define PC1 2048                 // k_tail blocks / partial stride

// fp16 <-> fp32 helpers via native _Float16
union HU { u16 u; _Float16 h; };
__device__ __forceinline__ float h2f(u16 u){ HU x; x.u=u; return (float)x.h; }
__device__ __forceinline__ u16 f2h(float f){ HU x; x.h=(_Float16)f; return x.u; }
#define H_ONE  0x3C00u   // 1.0 erode-neutral (values in [0,1])
#define H_ZERO 0x0000u   // 0.0 dilate-neutral

__device__ __forceinline__ double wred(double v){
  #pragma unroll
  for(int o=32;o;o>>=1) v += __shfl_down(v, o);
  return v;
}

// ---------------- init: prob(fp16), bitmasks, y8, mm-init, dice/ce/conn sums ----------------
__global__ __launch_bounds__(256) void k_init(const float* __restrict__ net, const int* __restrict__ tgt,
    u16* __restrict__ img, u64* __restrict__ ybits, u64* __restrict__ hbits,
    u64* __restrict__ bimg2, u8* __restrict__ y8, u32* __restrict__ mm, double* __restrict__ part)
{
  if (blockIdx.x==0 && threadIdx.x<8)
    mm[threadIdx.x] = (threadIdx.x==2||threadIdx.x==3||threadIdx.x==6||threadIdx.x==7) ? 0xFFFFFFFFu : 0u;
  int n = blockIdx.x*256 + threadIdx.x;   // exactly NTOT threads
  int b = n >> 20;
  int v = n & (VOL-1);
  const float* nb = net + (size_t)b*(2*VOL);
  float x0 = nb[v], x1 = nb[VOL+v];
  int t = tgt[n];
  int yb = (t>0) ? 1 : 0;
  float p = 1.f/(1.f+__expf(x0-x1));
  img[n] = f2h(p);
  y8[n] = (u8)yb;
  u64 wy = __ballot(yb);
  u64 wh = __ballot(x1 > x0);
  if((threadIdx.x & 63)==0){
    int wi = n>>6;
    ybits[wi]=wy; hbits[wi]=wh;
    bimg2[wi]=wy; bimg2[NWORDS+wi]=wh;
  }
  float mx = fmaxf(x0,x1);
  float lse = mx + __logf(__expf(x0-mx)+__expf(x1-mx));
  double ce = (double)(lse - (yb ? x1 : x0));
  double tp = (double)p * yb;
  double spr = (double)p;
  double sy = (double)yb;
  double conn = (double)((int)((x0>0.5f)!=(yb!=0)) + (int)((x1>0.5f)!=(yb!=0)));
  __shared__ double sw[5][4];
  int wid = threadIdx.x>>6, lane = threadIdx.x&63;
  double vals[5] = {ce,tp,spr,sy,conn};
  #pragma unroll
  for(int s=0;s<5;s++){ double r = wred(vals[s]); if(lane==0) sw[s][wid]=r; }
  __syncthreads();
  if(threadIdx.x==0){
    #pragma unroll
    for(int s=0;s<5;s++) part[(size_t)s*PC0 + blockIdx.x] = sw[s][0]+sw[s][1]+sw[s][2]+sw[s][3];
  }
}

// ---------------- EDT per-element bodies (separable Chebyshev, min(16, dist)) ----------------
__device__ __forceinline__ void edt_px_one(const u64* __restrict__ yb, const u64* __restrict__ hb,
                                           u8* __restrict__ d, int g){
  int m = g >> 21;
  int n = g & (NTOT-1);
  const u64* bits = m ? hb : yb;
  int x = n & 127;
  int row = n >> 7;
  u64 w0 = bits[row*2], w1 = bits[row*2+1];
  int a = x - 31;
  u64 win;
  if (a < 0)        win = w0 << (-a);
  else if (a == 0)  win = w0;
  else if (a < 64)  win = (w0 >> a) | (w1 << (64-a));
  else              win = w1 >> (a-64);
  if (x < 31)  win |= (1ull << (31-x)) - 1;
  if (x > 95)  win |= (~0ull) << (159-x);
  u64 inv = ~win;
  u64 tl = inv & 0xFFFFFFFFull;
  u64 tr = inv >> 31;
  int dl = tl ? (31 - (63 - __clzll(tl))) : 99;
  int dr = tr ? (__ffsll((unsigned long long)tr) - 1) : 99;
  d[(size_t)g] = (u8)min(min(dl, dr), 16);
}

template<int STRIDE, int LIM, int SHIFT>
__device__ __forceinline__ int edt_pyz_one(const u8* __restrict__ din, u8* __restrict__ dout, int g){
  int n = g & (NTOT-1);
  int c = (n >> SHIFT) & (LIM-1);
  size_t idx = (size_t)g;
  int best = din[idx];
  #pragma unroll 4
  for (int k=1; k<=16; ++k){
    if (best <= k) break;
    int v = 255;
    if (c-k >= 0)  v = din[idx - (size_t)k*STRIDE];
    if (c+k < LIM) v = min(v, (int)din[idx + (size_t)k*STRIDE]);
    best = min(best, max(k, v));
  }
  dout[idx] = (u8)best;
  return best;
}

// ---------------- mega: fskel tiles (blocks 0..2047) + EDT side-task (blocks 2048..2559) ----
// fskel: fp16 E-chain step, tile 32x8x4, division-free indexing, 5 barriers.
// LDS A: [8][12][36] (E_k halo2, reused as B1 [6][10][32]); LDS B: [6][10][34] (E_{k+1}, reused as B2 [6][8][32]).
template<bool INIT>
__global__ __launch_bounds__(256) void mega(
    const u16* __restrict__ imgin, u16* __restrict__ imgout, u16* __restrict__ skel,
    const u64* __restrict__ ybits, const u64* __restrict__ hbits, const u64* __restrict__ skel2,
    u8* __restrict__ dA, u8* __restrict__ dB, u32* __restrict__ mm,
    int wimg, int task)
{
  __shared__ u16 bufA[3456];
  __shared__ u16 bufB[2040];
  int bid = blockIdx.x;
  int tid = threadIdx.x;
  if (bid < 2048){
    int xb = bid&3, yb=(bid>>2)&15, zb=(bid>>6)&15, b=bid>>10;
    int X0=xb*32, Y0=yb*8, Z0=zb*4;
    const u16* vin = imgin + (size_t)b*VOL;
    u16* vout = imgout + (size_t)b*VOL;
    u16* skl = skel + (size_t)b*VOL;
    // ---- P0: load E_k [8][12][36], OOB -> 1.0 ----
    {
      int y0 = tid/36, x0 = tid - y0*36;
      int gy0 = Y0-2+y0, gx0 = X0-2+x0;
      bool ok0 = ((unsigned)gy0<128u) & ((unsigned)gx0<128u);
      int gb0 = (gy0<<7)+gx0;
      int t1 = tid+256;
      int y1 = t1/36, x1 = t1 - y1*36;
      int gy1 = Y0-2+y1, gx1 = X0-2+x1;
      bool hv1 = tid<176;
      bool ok1 = ((unsigned)gy1<128u) & ((unsigned)gx1<128u);
      int gb1 = (gy1<<7)+gx1;
      #pragma unroll
      for (int z=0; z<8; ++z){
        int gz = Z0-2+z;
        bool zok = (unsigned)gz<64u;
        int zb2 = gz<<14;
        bufA[z*432+tid] = (zok&ok0) ? vin[zb2+gb0] : (u16)H_ONE;
        if (hv1) bufA[z*432+t1] = (zok&ok1) ? vin[zb2+gb1] : (u16)H_ONE;
      }
    }
    __syncthreads();
    // ---- P1: E_{k+1} = erode7(E_k) on [6][10][34], OOB position -> 0.0 ----
    {
      int y0 = tid/34, x0 = tid - y0*34;
      bool ok0 = ((unsigned)(Y0-1+y0)<128u) & ((unsigned)(X0-1+x0)<128u);
      int c0 = (y0+1)*36 + (x0+1);
      int t1 = tid+256;
      int y1 = t1/34, x1 = t1 - y1*34;
      bool hv1 = tid<84;
      bool ok1 = ((unsigned)(Y0-1+y1)<128u) & ((unsigned)(X0-1+x1)<128u);
      int c1 = (y1+1)*36 + (x1+1);
      #pragma unroll
      for (int z=0; z<6; ++z){
        bool zok = (unsigned)(Z0-1+z)<64u;
        int c = (z+1)*432 + c0;
        u32 m = min((u32)bufA[c-1], (u32)bufA[c]);
        m = min(m, (u32)bufA[c+1]);
        m = min(m, min((u32)bufA[c-36],(u32)bufA[c+36]));
        m = min(m, min((u32)bufA[c-432],(u32)bufA[c+432]));
        bufB[z*340+tid] = (zok&ok0) ? (u16)m : (u16)H_ZERO;
        if (hv1){
          int cc = (z+1)*432 + c1;
          u32 m1 = min((u32)bufA[cc-1], (u32)bufA[cc]);
          m1 = min(m1, (u32)bufA[cc+1]);
          m1 = min(m1, min((u32)bufA[cc-36],(u32)bufA[cc+36]));
          m1 = min(m1, min((u32)bufA[cc-432],(u32)bufA[cc+432]));
          bufB[z*340+t1] = (zok&ok1) ? (u16)m1 : (u16)H_ZERO;
        }
      }
    }
    __syncthreads();
    // ---- P2: snapshot E_k center; write E_{k+1} center ----
    int yy0 = tid>>5, xx0 = tid&31;
    u16 ek[4];
    {
      int nb0 = ((Y0+yy0)<<7)+(X0+xx0);
      #pragma unroll
      for(int j=0;j<4;j++){
        ek[j] = bufA[(j+2)*432+(yy0+2)*36+(xx0+2)];
        if(wimg) vout[((Z0+j)<<14)+nb0] = bufB[(j+1)*340+(yy0+1)*34+(xx0+1)];
      }
    }
    __syncthreads();
    // ---- P3: B1[6][10][32] = xmax(E_{k+1}) -> bufA ----
    {
      int p0 = tid;            // y=p>>5 (0..7 for tid<256), x=p&31
      int y0 = p0>>5, x0 = p0&31;
      int r0 = y0*34 + x0;
      bool hv1 = tid<64;
      int p1 = tid+256;        // covers y 8..9
      int y1 = p1>>5, x1 = p1&31;
      int r1 = y1*34 + x1;
      #pragma unroll
      for (int z=0; z<6; ++z){
        int cb = z*340;
        u32 m = max((u32)bufB[cb+r0], (u32)bufB[cb+r0+1]);
        bufA[z*320+p0] = (u16)max(m, (u32)bufB[cb+r0+2]);
        if (hv1){
          u32 m1 = max((u32)bufB[cb+r1], (u32)bufB[cb+r1+1]);
          bufA[z*320+p1] = (u16)max(m1, (u32)bufB[cb+r1+2]);
        }
      }
    }
    __syncthreads();
    // ---- P4: B2[6][8][32] = ymax(B1) -> bufB ----
    {
      int r0 = yy0*32 + xx0;
      #pragma unroll
      for (int z=0; z<6; ++z){
        int cb = z*320 + r0;
        u32 m = max((u32)bufA[cb], (u32)bufA[cb+32]);
        bufB[z*256+tid] = (u16)max(m, (u32)bufA[cb+64]);
      }
    }
    __syncthreads();
    // ---- P5: open = zmax(B2); skel update ----
    {
      int nb0 = ((Y0+yy0)<<7)+(X0+xx0);
      #pragma unroll
      for(int j=0;j<4;j++){
        int c = j*256 + tid;
        u32 m = max((u32)bufB[c], (u32)bufB[c+256]);
        m = max(m, (u32)bufB[c+512]);
        float d = fmaxf(h2f(ek[j]) - h2f((u16)m), 0.f);
        int n = ((Z0+j)<<14)+nb0;
        if (INIT) skl[n] = f2h(d);
        else {
          float so = h2f(skl[n]);
          skl[n] = f2h(so + fmaxf(d - so*d, 0.f));
        }
      }
    }
  } else {
    // ---------------- EDT side-task blocks ----------------
    int eb = bid - 2048;                 // 0..511
    if (task == 1){
      for (int g = eb*256+tid; g < 2*NTOT; g += 512*256)
        edt_px_one(ybits, hbits, dA, g);
    } else if (task == 2){
      for (int g = eb*256+tid; g < 2*NTOT; g += 512*256)
        edt_pyz_one<128,128,7>(dA, dB, g);
    } else if (task == 3){
      u32 mx0=0,mx1=0,mx2=0,mx3=0;
      u32 mn0=~0u,mn1=~0u,mn2=~0u,mn3=~0u;
      for (int g = eb*256+tid; g < 2*NTOT; g += 512*256){
        int best = edt_pyz_one<16384,64,14>(dB, dA, g);
        int m = g>>21, n = g&(NTOT-1);
        int wi = n>>6, bit = n&63;
        u64 sbit = m ? (skel2[NWORDS+wi] & hbits[wi]) : skel2[wi];
        u32 r = (u32)((sbit>>bit)&1ull) ? (u32)best : 0u;
        int cat = m*2 + (n>>20);
        mx0 = (cat==0) ? max(mx0,r) : mx0;  mn0 = (cat==0) ? min(mn0,r) : mn0;
        mx1 = (cat==1) ? max(mx1,r) : mx1;  mn1 = (cat==1) ? min(mn1,r) : mn1;
        mx2 = (cat==2) ? max(mx2,r) : mx2;  mn2 = (cat==2) ? min(mn2,r) : mn2;
        mx3 = (cat==3) ? max(mx3,r) : mx3;  mn3 = (cat==3) ? min(mn3,r) : mn3;
      }
      #pragma unroll
      for(int o=32;o;o>>=1){
        mx0 = max(mx0,(u32)__shfl_down((int)mx0,o)); mn0 = min(mn0,(u32)__shfl_down((int)mn0,o));
        mx1 = max(mx1,(u32)__shfl_down((int)mx1,o)); mn1 = min(mn1,(u32)__shfl_down((int)mn1,o));
        mx2 = max(mx2,(u32)__shfl_down((int)mx2,o)); mn2 = min(mn2,(u32)__shfl_down((int)mn2,o));
        mx3 = max(mx3,(u32)__shfl_down((int)mx3,o)); mn3 = min(mn3,(u32)__shfl_down((int)mn3,o));
      }
      if ((tid&63)==0){
        atomicMax(&mm[0], mx0); atomicMin(&mm[2], mn0);   // cat0: sel0,b0
        atomicMax(&mm[1], mx1); atomicMin(&mm[3], mn1);   // cat1: sel0,b1
        atomicMax(&mm[4], mx2); atomicMin(&mm[6], mn2);   // cat2: sel1,b0
        atomicMax(&mm[5], mx3); atomicMin(&mm[7], mn3);   // cat3: sel1,b1
      }
    }
  }
}

// ---------------- systolic fused binary soft-skel iteration (bit-planes), chunk 2 ----------------
__device__ __forceinline__ u64 berode_x(const u64* P, int tid){
  u64 c = P[tid];
  if (tid & 1) return c & ((c<<1)|(P[tid-1]>>63)) & ((c>>1)|(1ull<<63));
  else         return c & ((c<<1)|1ull) & ((c>>1)|(P[tid+1]<<63));
}
__device__ __forceinline__ u64 bdilate_x(const u64* P, int tid){
  u64 c = P[tid];
  if (tid & 1) return c | (c<<1) | (P[tid-1]>>63) | (c>>1);
  else         return c | (c<<1) | (c>>1) | (P[tid+1]<<63);
}

template<bool INIT>
__global__ __launch_bounds__(256) void bskel(const u64* __restrict__ imgin, u64* __restrict__ imgout,
                                             u64* __restrict__ skel)
{
  __shared__ u64 simg[4][256];
  __shared__ u64 se1[6][256];
  __shared__ u64 se2[2][256];
  __shared__ u64 sM[4][256];
  int bid = blockIdx.x;
  int tzb = bid & 31, b = (bid>>5)&1, m = bid>>6;
  int z0 = tzb*2, z1 = z0+2;
  size_t base = (size_t)m*NWORDS + (size_t)b*16384;
  const u64* vin = imgin + base;
  u64* vout = imgout + base;
  u64* skl = skel + base;
  int tid = threadIdx.x;
  int y = tid>>1;

  for (int s = z0-3; s <= z1+6; ++s){
    if (s <= z1+2)
      simg[(s+96)&3][tid] = ((unsigned)s<64u) ? vin[(s<<8)+tid] : ~0ull;
    { int t = s-2;
      if (t >= z0-2 && t <= z1+1){
        u64 r = ~0ull;
        if ((unsigned)t<64u){
          const u64* P = simg[(t+96)&3];
          if (INIT) r = P[tid];
          else {
            r = berode_x(P, tid);
            if(y>0)   r &= P[tid-2];
            if(y<127) r &= P[tid+2];
            r &= simg[(t-1+96)&3][tid] & simg[(t+1+96)&3][tid];
          }
        }
        se1[(t+96)%6][tid] = r;
      }
    }
    { int t = s-4;
      if (t >= z0-1 && t <= z1){
        u64 r = 0;
        if ((unsigned)t<64u){
          const u64* P = se1[(t+96)%6];
          r = berode_x(P, tid);
          if(y>0)   r &= P[tid-2];
          if(y<127) r &= P[tid+2];
          r &= se1[(t-1+96)%6][tid] & se1[(t+1+96)%6][tid];
        }
        se2[(t+96)&1][tid] = r;
      }
    }
    { int t = s-5;
      if (t >= z0-1 && t <= z1){
        const u64* P = se2[(t+96)&1];
        u64 dm = bdilate_x(P, tid);
        if(y>0)   dm |= bdilate_x(P, tid-2);
        if(y<127) dm |= bdilate_x(P, tid+2);
        sM[(t+96)&3][tid] = dm;
      }
    }
    { int z = s-7;
      if (z >= z0 && z < z1){
        u64 open_ = sM[(z-1+96)&3][tid] | sM[(z+96)&3][tid] | sM[(z+1+96)&3][tid];
        u64 e1v = se1[(z+96)%6][tid];
        u64 d = e1v & ~open_;
        int gw = (z<<8)+tid;
        if (INIT) skl[gw] = d;
        else { skl[gw] |= d; vout[gw] = e1v; }
      }
    }
    __syncthreads();
  }
}

// ---------------- fused sobel + final reduce, 4 voxels per thread ----------------
__global__ __launch_bounds__(256) void k_tail(const float* __restrict__ net, const u16* __restrict__ skelp,
    const u64* __restrict__ ybits, const u64* __restrict__ hbits, const u64* __restrict__ skel2,
    const u8* __restrict__ acc, const u8* __restrict__ y8, const u32* __restrict__ mm,
    double* __restrict__ part1)
{
  float rmaxT_[2], rminT_[2], rmaxH_[2], rminH_[2];
  for(int b=0;b<2;b++){
    rmaxT_[b]=fmaxf((float)mm[b],1.f);   rminT_[b]=fmaxf((float)mm[2+b],1.f);
    rmaxH_[b]=fmaxf((float)mm[4+b],1.f); rminH_[b]=fmaxf((float)mm[6+b],1.f);
  }
  const int SMi[3]={1,2,1}, DVi[3]={-1,0,1};
  int r = blockIdx.x*256 + threadIdx.x;   // exactly NTOT/4 threads
  int n0 = r<<2;
  int b = n0>>20, v0 = n0&(VOL-1);
  int xb = n0&127, y=(n0>>7)&127, z=(n0>>14)&63;
  const float* P = net + (size_t)b*(2*VOL);
  const u8* Y8 = y8 + ((size_t)b<<20);
  float gpx[4]={0,0,0,0}, gpy[4]={0,0,0,0}, gpz[4]={0,0,0,0};
  int   gtx[4]={0,0,0,0}, gty[4]={0,0,0,0}, gtz[4]={0,0,0,0};
  #pragma unroll
  for(int da=0;da<3;da++){
    int zz=z+da-1; if((unsigned)zz>=64u) continue;
    #pragma unroll
    for(int db=0;db<3;db++){
      int yy=y+db-1; if((unsigned)yy>=128u) continue;
      int rb_ = (zz<<14)+(yy<<7)+xb;
      float pv[6]; int tv[6];
      #pragma unroll
      for(int j=0;j<6;j++){
        int xx = xb-1+j;
        bool ok = (unsigned)xx<128u;
        pv[j] = ok ? P[rb_-1+j] : 0.f;
        tv[j] = ok ? (int)Y8[rb_-1+j] : 0;
      }
      int smb=SMi[db], sma=SMi[da], dva=DVi[da];
      #pragma unroll
      for(int e=0;e<4;e++){
        float ep = pv[e+2]-pv[e], sp = pv[e]+2.f*pv[e+1]+pv[e+2];
        gpx[e] += (float)smb*ep; gpy[e] += (float)sma*ep; gpz[e] += (float)dva*sp;
        int et = tv[e+2]-tv[e], st = tv[e]+2*tv[e+1]+tv[e+2];
        gtx[e] += smb*et; gty[e] += sma*et; gtz[e] += dva*st;
      }
    }
  }
  float4 X0 = *(const float4*)&P[v0];
  float4 X1 = *(const float4*)&P[VOL+v0];
  ushort4 SK = *(const ushort4*)&skelp[n0];
  uchar4 DT = *(const uchar4*)&acc[n0];
  uchar4 DH = *(const uchar4*)&acc[NTOT+n0];
  int wi0 = n0>>6, bit0 = n0&63;
  int ybq = (int)((ybits[wi0]>>bit0)&0xFull);
  int hdq = (int)((hbits[wi0]>>bit0)&0xFull);
  int sTq = (int)((skel2[wi0]>>bit0)&0xFull);
  int sHq = (int)((skel2[NWORDS+wi0]>>bit0)&0xFull);
  float fsob=0,fcl1=0,fcl2=0,fcl3=0,fcl4=0,fi1=0,fun1=0,fi2=0,fun2=0;
  #pragma unroll
  for(int e=0;e<4;e++){
    float ftx=(float)gtx[e], fty=(float)gty[e], ftz=(float)gtz[e];
    float np_=sqrtf(gpx[e]*gpx[e]+gpy[e]*gpy[e]+gpz[e]*gpz[e]);
    float nt_=sqrtf(ftx*ftx+fty*fty+ftz*ftz);
    float ip=1.f/fmaxf(np_,1e-12f), it=1.f/fmaxf(nt_,1e-12f);
    float num=(gpx[e]*ftx+gpy[e]*fty+gpz[e]*ftz)*ip*it;
    float den=fmaxf((np_*ip)*(nt_*it),1e-8f);
    fsob += num/den;
    int yb=(ybq>>e)&1, hd=(hdq>>e)&1, sT=(sTq>>e)&1, sH=(sHq>>e)&1;
    float dT=(float)((const u8*)&DT)[e], dH=(float)((const u8*)&DH)[e];
    float x0v=((const float*)&X0)[e], x1v=((const float*)&X1)[e];
    float p = 1.f/(1.f+__expf(x0v-x1v));
    float sk = h2f(((const u16*)&SK)[e]);
    fcl1 += sk*(float)yb;
    fcl2 += sk;
    float q_vl = yb ? fminf(dT,rmaxT_[b])/rmaxT_[b] : 0.f;
    if (sT){
      fcl3 += p; fcl4 += 1.f;
      float t=(rmaxT_[b]-dT+rminT_[b])/rmaxT_[b]; float q_sl=t*t;
      float q_vp = fminf(dH,rmaxH_[b])/rmaxH_[b]*p;
      fi2  += q_sl*__powf(q_vp+1e-4f,0.7f)*q_sl;
      fun2 += q_sl*(0.1f*q_vp+0.9f*q_sl);
    }
    if (sH & hd){
      float t=(rmaxH_[b]-dH+rminH_[b])/rmaxH_[b]; float q_sp=t*t*p;
      fi1  += q_sp*__powf(q_sp+1e-4f,0.7f)*q_vl;
      fun1 += q_sp*(0.1f*q_sp+0.9f*q_vl);
    }
  }
  __shared__ double sw[9][4];
  int wid = threadIdx.x>>6, lane = threadIdx.x&63;
  double vals[9] = {fsob,fcl1,fcl2,fcl3,fcl4,fi1,fun1,fi2,fun2};
  #pragma unroll
  for(int s=0;s<9;s++){ double rr = wred(vals[s]); if(lane==0) sw[s][wid]=rr; }
  __syncthreads();
  if(threadIdx.x==0){
    #pragma unroll
    for(int s=0;s<9;s++) part1[(size_t)s*PC1 + blockIdx.x] = sw[s][0]+sw[s][1]+sw[s][2]+sw[s][3];
  }
}

// ---------------- two-stage finalize ----------------
__global__ __launch_bounds__(256) void k_reduce_mid(const double* __restrict__ part0,
                                                    const double* __restrict__ part1,
                                                    double* __restrict__ tot){
  int s = blockIdx.x;  // 0..13
  const double* src; int n;
  if (s < 5){ src = part0 + (size_t)s*PC0; n = PC0; }
  else      { src = part1 + (size_t)(s-5)*PC1; n = PC1; }
  double v=0;
  for(int i=threadIdx.x;i<n;i+=256) v += src[i];
  __shared__ double sd[256];
  sd[threadIdx.x]=v; __syncthreads();
  for(int k=128;k>0;k>>=1){ if((int)threadIdx.x<k) sd[threadIdx.x]+=sd[threadIdx.x+k]; __syncthreads(); }
  if(threadIdx.x==0) tot[s]=sd[0];
}

__global__ void k_fin(const double* __restrict__ tot, float* __restrict__ out){
  if(threadIdx.x==0 && blockIdx.x==0){
    const double N = (double)NTOT;
    double ce = tot[0]/N;
    double tp=tot[1], fp=tot[2]-tot[1], fn=tot[3]-tot[1];
    double dice = -((2.0*tp+1e-5)/(2.0*tp+fp+fn+1e-5));
    double conn = tot[4]/(2.0*N);
    double dir  = 1.0 - tot[5]/N;
    double tprec = (tot[6]+1.0)/(tot[7]+1.0);
    double tsens = (tot[8]+1.0)/(tot[9]+1.0);
    double cld = 1.0 - 2.0*tprec*tsens/(tprec+tsens);
    double u1 = 1.0 - (tot[10]+1.0)/(tot[11]+1.0);
    double u2 = 1.0 - (tot[12]+1.0)/(tot[13]+1.0);
    out[0] = (float)(dice+ce+cld+dir+conn+u1+u2);
  }
}

extern "C" void kernel_launch(void* const* d_in, const int* in_sizes, int n_in,
                              void* d_out, int out_size, void* d_ws, size_t ws_size,
                              hipStream_t stream)
{
  (void)in_sizes; (void)n_in; (void)out_size; (void)ws_size;
  const float* net = (const float*)d_in[0];
  const int*   tgt = (const int*)d_in[1];
  float* out = (float*)d_out;
  char* w = (char*)d_ws;
  const size_t MB = 1024*1024;
  u16* F1 = (u16*)(w + 0*MB);              // prob img ping (fp16)
  u16* F2 = (u16*)(w + 4*MB);              // skel_pred (fp16)
  u16* F3 = (u16*)(w + 8*MB);              // img pong (fp16)
  u64* ybits = (u64*)(w + 12*MB);
  u64* hbits = ybits + NWORDS;
  u64* skel2 = hbits + NWORDS;             // [T][H]
  u64* bping = skel2 + 2*NWORDS;           // [T][H]
  u64* bpong = bping + 2*NWORDS;
  u8*  dA    = (u8*)(bpong + 2*NWORDS);    // 4 MB
  u8*  dB    = dA + (size_t)2*NTOT;        // 4 MB
  u8*  y8    = dB + (size_t)2*NTOT;        // 2 MB
  double* part0 = (double*)(y8 + (size_t)NTOT);
  double* part1 = part0 + (size_t)5*PC0;
  double* tot   = part1 + (size_t)9*PC1;
  u32* mm  = (u32*)(tot + 16);

  k_init<<<PC0, 256, 0, stream>>>(net, tgt, F1, ybits, hbits, bping, y8, mm, part0);

  // binary soft_skel for y_true and hard: 11 systolic dispatches (128 blocks each)
  bskel<true><<<128,256,0,stream>>>(bping, bpong, skel2);
  {
    u64* pi=bping; u64* po=bpong;
    for(int i=0;i<10;i++){ bskel<false><<<128,256,0,stream>>>(pi,po,skel2); u64* t=pi; pi=po; po=t; }
  }

  // float soft_skel(prob, 10): 11 mega dispatches (fskel tiles + EDT side-tasks)
  mega<true><<<2560,256,0,stream>>>(F1, F3, F2, ybits, hbits, skel2, dA, dB, mm, 1, 1);
  {
    u16* pi=F3; u16* po=F1;
    for(int i=0;i<10;i++){
      int task = (i==0) ? 2 : (i==1) ? 3 : 0;
      mega<false><<<2560,256,0,stream>>>(pi, po, F2, ybits, hbits, skel2, dA, dB, mm, (i<9)?1:0, task);
      u16* t=pi; pi=po; po=t;
    }
  }

  k_tail<<<PC1,256,0,stream>>>(net, F2, ybits, hbits, skel2, dA, y8, mm, part1);
  k_reduce_mid<<<14,256,0,stream>>>(part0, part1, tot);
  k_fin<<<1,64,0,stream>>>(tot, out);
}

// Round 9
// 378.984 us; speedup vs baseline: 1.4831x; 1.4831x over previous
//
#include <hip/hip_runtime.h>
#include <math.h>

typedef unsigned long long u64;
typedef unsigned int u32;
typedef unsigned short u16;
typedef unsigned char u8;

#define VOL 1048576              // 64*128*128
#define NTOT 2097152             // 2 batches
#define NWORDS 32768             // NTOT/64
#define PC0 8192                 // k_init blocks / partial stride
#define PC1 2048                 // k_tail blocks / partial stride

// fp16 <-> fp32 helpers via native _Float16
union HU { u16 u; _Float16 h; };
__device__ __forceinline__ float h2f(u16 u){ HU x; x.u=u; return (float)x.h; }
__device__ __forceinline__ u16 f2h(float f){ HU x; x.h=(_Float16)f; return x.u; }
#define H_ONE  0x3C00u   // 1.0 erode-neutral (values in [0,1])
#define H_ZERO 0x0000u   // 0.0 dilate-neutral

__device__ __forceinline__ double wred(double v){
  #pragma unroll
  for(int o=32;o;o>>=1) v += __shfl_down(v, o);
  return v;
}

// ---------------- init: prob(fp16), bitmasks, y8, dice/ce/conn sums ----------------
__global__ __launch_bounds__(256) void k_init(const float* __restrict__ net, const int* __restrict__ tgt,
    u16* __restrict__ img, u64* __restrict__ ybits, u64* __restrict__ hbits,
    u64* __restrict__ bimg2, u8* __restrict__ y8, double* __restrict__ part)
{
  int n = blockIdx.x*256 + threadIdx.x;   // exactly NTOT threads
  int b = n >> 20;
  int v = n & (VOL-1);
  const float* nb = net + (size_t)b*(2*VOL);
  float x0 = nb[v], x1 = nb[VOL+v];
  int t = tgt[n];
  int yb = (t>0) ? 1 : 0;
  float p = 1.f/(1.f+__expf(x0-x1));
  img[n] = f2h(p);
  y8[n] = (u8)yb;
  u64 wy = __ballot(yb);
  u64 wh = __ballot(x1 > x0);
  if((threadIdx.x & 63)==0){
    int wi = n>>6;
    ybits[wi]=wy; hbits[wi]=wh;
    bimg2[wi]=wy; bimg2[NWORDS+wi]=wh;
  }
  float mx = fmaxf(x0,x1);
  float lse = mx + __logf(__expf(x0-mx)+__expf(x1-mx));
  double ce = (double)(lse - (yb ? x1 : x0));
  double tp = (double)p * yb;
  double spr = (double)p;
  double sy = (double)yb;
  double conn = (double)((int)((x0>0.5f)!=(yb!=0)) + (int)((x1>0.5f)!=(yb!=0)));
  __shared__ double sw[5][4];
  int wid = threadIdx.x>>6, lane = threadIdx.x&63;
  double vals[5] = {ce,tp,spr,sy,conn};
  #pragma unroll
  for(int s=0;s<5;s++){ double r = wred(vals[s]); if(lane==0) sw[s][wid]=r; }
  __syncthreads();
  if(threadIdx.x==0){
    #pragma unroll
    for(int s=0;s<5;s++) part[(size_t)s*PC0 + blockIdx.x] = sw[s][0]+sw[s][1]+sw[s][2]+sw[s][3];
  }
}

// ---------------- fskel2: TWO soft-skel iterations per dispatch (E-chain), tile 32x8x4 ----
// A = E_k halo3 [10][14][38]; B = E_{k+1} halo2 [8][12][36] (OOB->1.0, erode-neutral;
// dilate consumer predicates edges itself); C = E_{k+2} halo1 [6][10][34] (OOB->0.0).
// Reuse: X1 -> A[0:1920], X2 -> A[1920:3840] ([6][10][32], stride 320);
//        Y1 -> B[0:1536], Y2 -> B[1536:3072] ([6][8][32], stride 256).
template<bool INIT>
__global__ __launch_bounds__(256) void fskel2(const u16* __restrict__ imgin, u16* __restrict__ imgout,
                                              u16* __restrict__ skel, int wimg)
{
  __shared__ u16 A_[5320];
  __shared__ u16 B_[3456];
  __shared__ u16 C_[2040];
  int bid = blockIdx.x;
  int xb = bid&3, yb=(bid>>2)&15, zb=(bid>>6)&15, b=bid>>10;
  int X0=xb*32, Y0=yb*8, Z0=zb*4;
  const u16* vin = imgin + (size_t)b*VOL;
  u16* vout = imgout + (size_t)b*VOL;
  u16* skl = skel + (size_t)b*VOL;
  int tid = threadIdx.x;
  int yy0 = tid>>5, xx0 = tid&31;

  // ---- P0: load A = E_k halo3, OOB -> 1.0 ----
  #pragma unroll
  for (int s0=0; s0<3; ++s0){
    int p = tid + s0*256;
    if (p < 532){
      int y = p/38, x = p - y*38;
      int gy = Y0-3+y, gx = X0-3+x;
      bool ok = ((unsigned)gy<128u) & ((unsigned)gx<128u);
      int gb = (gy<<7)+gx;
      #pragma unroll
      for (int z=0; z<10; ++z){
        int gz = Z0-3+z;
        bool zok = (unsigned)gz<64u;
        A_[z*532+p] = (zok&ok) ? vin[(gz<<14)+gb] : (u16)H_ONE;
      }
    }
  }
  __syncthreads();
  // ---- P1: B = erode7(A) on halo2, OOB -> 1.0 (erode-neutral); snapshot ek0 ----
  u16 ek0[4];
  #pragma unroll
  for(int j=0;j<4;j++) ek0[j] = A_[(j+3)*532 + (yy0+3)*38 + (xx0+3)];
  #pragma unroll
  for (int s0=0; s0<2; ++s0){
    int p = tid + s0*256;
    if (p < 432){
      int y = p/36, x = p - y*36;
      int gy = Y0-2+y, gx = X0-2+x;
      bool ok = ((unsigned)gy<128u) & ((unsigned)gx<128u);
      #pragma unroll
      for (int z=0; z<8; ++z){
        bool zok = (unsigned)(Z0-2+z)<64u;
        u32 v = H_ONE;
        if (zok & ok){
          int c = (z+1)*532 + (y+1)*38 + (x+1);
          u32 m = min((u32)A_[c-1], (u32)A_[c]);
          m = min(m, (u32)A_[c+1]);
          m = min(m, min((u32)A_[c-38],(u32)A_[c+38]));
          m = min(m, min((u32)A_[c-532],(u32)A_[c+532]));
          v = m;
        }
        B_[z*432+p] = (u16)v;
      }
    }
  }
  __syncthreads();
  // ---- P2: C = erode7(B) on halo1, OOB -> 0.0; write E_{k+2} center; snapshot ek1 ----
  u16 ek1[4];
  #pragma unroll
  for(int j=0;j<4;j++) ek1[j] = B_[(j+2)*432 + (yy0+2)*36 + (xx0+2)];
  #pragma unroll
  for (int s0=0; s0<2; ++s0){
    int p = tid + s0*256;
    if (p < 340){
      int y = p/34, x = p - y*34;
      int gy = Y0-1+y, gx = X0-1+x;
      bool ok = ((unsigned)gy<128u) & ((unsigned)gx<128u);
      bool ctr_yx = (y>=1) & (y<=8) & (x>=1) & (x<=32);
      #pragma unroll
      for (int z=0; z<6; ++z){
        int gz = Z0-1+z;
        bool zok = (unsigned)gz<64u;
        u32 v = H_ZERO;
        if (zok & ok){
          int c = (z+1)*432 + (y+1)*36 + (x+1);
          u32 m = min((u32)B_[c-1], (u32)B_[c]);
          m = min(m, (u32)B_[c+1]);
          m = min(m, min((u32)B_[c-36],(u32)B_[c+36]));
          m = min(m, min((u32)B_[c-432],(u32)B_[c+432]));
          v = m;
        }
        C_[z*340+p] = (u16)v;
        if (wimg && ctr_yx && z>=1 && z<=4)
          vout[(gz<<14)+(gy<<7)+gx] = (u16)v;
      }
    }
  }
  __syncthreads();
  // ---- P3: X1 = xmax(B) (edge-predicated), X2 = xmax(C) -> A space ----
  #pragma unroll
  for (int s0=0; s0<2; ++s0){
    int p = tid + s0*256;
    if (p < 320){
      int y = p>>5, x = p&31;
      int gy = Y0-1+y;
      int gx = X0+x;
      bool yok = (unsigned)gy<128u;
      bool xm = (gx>0), xp = (gx<127);
      #pragma unroll
      for (int z=0; z<6; ++z){
        bool zok = (unsigned)(Z0-1+z)<64u;
        int c = (z+1)*432 + (y+1)*36 + (x+1);
        u32 v = B_[c];
        u32 vm = xm ? (u32)B_[c-1] : 0u;
        u32 vp = xp ? (u32)B_[c+1] : 0u;
        v = max(v, max(vm, vp));
        A_[z*320+p] = (zok&yok) ? (u16)v : (u16)0;
        int c2 = z*340 + y*34 + x;
        u32 w = max((u32)C_[c2], max((u32)C_[c2+1],(u32)C_[c2+2]));
        A_[1920 + z*320+p] = (u16)w;
      }
    }
  }
  __syncthreads();
  // ---- P4: Y1 = ymax(X1), Y2 = ymax(X2) -> B space ----
  {
    int r0 = yy0*32 + xx0;
    #pragma unroll
    for (int z=0; z<6; ++z){
      int cb = z*320 + r0;
      u32 m1 = max((u32)A_[cb], (u32)A_[cb+32]);
      B_[z*256+tid] = (u16)max(m1, (u32)A_[cb+64]);
      u32 m2 = max((u32)A_[1920+cb], (u32)A_[1920+cb+32]);
      B_[1536+z*256+tid] = (u16)max(m2, (u32)A_[1920+cb+64]);
    }
  }
  __syncthreads();
  // ---- P5: open = zmax; two skel updates ----
  {
    int nb0 = ((Y0+yy0)<<7)+(X0+xx0);
    #pragma unroll
    for(int j=0;j<4;j++){
      int c = j*256 + tid;
      u32 o1 = max((u32)B_[c], (u32)B_[c+256]);
      o1 = max(o1, (u32)B_[c+512]);
      u32 o2 = max((u32)B_[1536+c], (u32)B_[1536+c+256]);
      o2 = max(o2, (u32)B_[1536+c+512]);
      float d0 = fmaxf(h2f(ek0[j]) - h2f((u16)o1), 0.f);
      float d1 = fmaxf(h2f(ek1[j]) - h2f((u16)o2), 0.f);
      int n = ((Z0+j)<<14)+nb0;
      float s;
      if (INIT) s = d0;
      else { s = h2f(skl[n]); s += fmaxf(d0 - s*d0, 0.f); }
      s += fmaxf(d1 - s*d1, 0.f);
      skl[n] = f2h(s);
    }
  }
}

// ---------------- fskel1: single iteration (last d-term), tile 32x8x4 ----------------
__global__ __launch_bounds__(256) void fskel1(const u16* __restrict__ imgin, u16* __restrict__ skel)
{
  __shared__ u16 bufA[3456];
  __shared__ u16 bufB[2040];
  int bid = blockIdx.x;
  int xb = bid&3, yb=(bid>>2)&15, zb=(bid>>6)&15, b=bid>>10;
  int X0=xb*32, Y0=yb*8, Z0=zb*4;
  const u16* vin = imgin + (size_t)b*VOL;
  u16* skl = skel + (size_t)b*VOL;
  int tid = threadIdx.x;
  // P0: load E_k [8][12][36], OOB -> 1.0
  {
    int y0 = tid/36, x0 = tid - y0*36;
    int gy0 = Y0-2+y0, gx0 = X0-2+x0;
    bool ok0 = ((unsigned)gy0<128u) & ((unsigned)gx0<128u);
    int gb0 = (gy0<<7)+gx0;
    int t1 = tid+256;
    int y1 = t1/36, x1 = t1 - y1*36;
    int gy1 = Y0-2+y1, gx1 = X0-2+x1;
    bool hv1 = tid<176;
    bool ok1 = ((unsigned)gy1<128u) & ((unsigned)gx1<128u);
    int gb1 = (gy1<<7)+gx1;
    #pragma unroll
    for (int z=0; z<8; ++z){
      int gz = Z0-2+z;
      bool zok = (unsigned)gz<64u;
      int zb2 = gz<<14;
      bufA[z*432+tid] = (zok&ok0) ? vin[zb2+gb0] : (u16)H_ONE;
      if (hv1) bufA[z*432+t1] = (zok&ok1) ? vin[zb2+gb1] : (u16)H_ONE;
    }
  }
  __syncthreads();
  // P1: E_{k+1} = erode7 on [6][10][34], OOB -> 0.0
  {
    int y0 = tid/34, x0 = tid - y0*34;
    bool ok0 = ((unsigned)(Y0-1+y0)<128u) & ((unsigned)(X0-1+x0)<128u);
    int c0 = (y0+1)*36 + (x0+1);
    int t1 = tid+256;
    int y1 = t1/34, x1 = t1 - y1*34;
    bool hv1 = tid<84;
    bool ok1 = ((unsigned)(Y0-1+y1)<128u) & ((unsigned)(X0-1+x1)<128u);
    int c1 = (y1+1)*36 + (x1+1);
    #pragma unroll
    for (int z=0; z<6; ++z){
      bool zok = (unsigned)(Z0-1+z)<64u;
      int c = (z+1)*432 + c0;
      u32 m = min((u32)bufA[c-1], (u32)bufA[c]);
      m = min(m, (u32)bufA[c+1]);
      m = min(m, min((u32)bufA[c-36],(u32)bufA[c+36]));
      m = min(m, min((u32)bufA[c-432],(u32)bufA[c+432]));
      bufB[z*340+tid] = (zok&ok0) ? (u16)m : (u16)H_ZERO;
      if (hv1){
        int cc = (z+1)*432 + c1;
        u32 m1 = min((u32)bufA[cc-1], (u32)bufA[cc]);
        m1 = min(m1, (u32)bufA[cc+1]);
        m1 = min(m1, min((u32)bufA[cc-36],(u32)bufA[cc+36]));
        m1 = min(m1, min((u32)bufA[cc-432],(u32)bufA[cc+432]));
        bufB[z*340+t1] = (zok&ok1) ? (u16)m1 : (u16)H_ZERO;
      }
    }
  }
  __syncthreads();
  // P2: snapshot E_k center
  int yy0 = tid>>5, xx0 = tid&31;
  u16 ek[4];
  #pragma unroll
  for(int j=0;j<4;j++) ek[j] = bufA[(j+2)*432+(yy0+2)*36+(xx0+2)];
  __syncthreads();
  // P3: B1[6][10][32] = xmax -> bufA
  {
    int p0 = tid;
    int y0 = p0>>5, x0 = p0&31;
    int r0 = y0*34 + x0;
    bool hv1 = tid<64;
    int p1 = tid+256;
    int y1 = p1>>5, x1 = p1&31;
    int r1 = y1*34 + x1;
    #pragma unroll
    for (int z=0; z<6; ++z){
      int cb = z*340;
      u32 m = max((u32)bufB[cb+r0], (u32)bufB[cb+r0+1]);
      bufA[z*320+p0] = (u16)max(m, (u32)bufB[cb+r0+2]);
      if (hv1){
        u32 m1 = max((u32)bufB[cb+r1], (u32)bufB[cb+r1+1]);
        bufA[z*320+p1] = (u16)max(m1, (u32)bufB[cb+r1+2]);
      }
    }
  }
  __syncthreads();
  // P4: B2[6][8][32] = ymax -> bufB
  {
    int r0 = yy0*32 + xx0;
    #pragma unroll
    for (int z=0; z<6; ++z){
      int cb = z*320 + r0;
      u32 m = max((u32)bufA[cb], (u32)bufA[cb+32]);
      bufB[z*256+tid] = (u16)max(m, (u32)bufA[cb+64]);
    }
  }
  __syncthreads();
  // P5: open = zmax; skel update
  {
    int nb0 = ((Y0+yy0)<<7)+(X0+xx0);
    #pragma unroll
    for(int j=0;j<4;j++){
      int c = j*256 + tid;
      u32 m = max((u32)bufB[c], (u32)bufB[c+256]);
      m = max(m, (u32)bufB[c+512]);
      float d = fmaxf(h2f(ek[j]) - h2f((u16)m), 0.f);
      int n = ((Z0+j)<<14)+nb0;
      float so = h2f(skl[n]);
      skl[n] = f2h(so + fmaxf(d - so*d, 0.f));
    }
  }
}

// ---------------- systolic fused binary soft-skel iteration (bit-planes), chunk 2 ----------------
__device__ __forceinline__ u64 berode_x(const u64* P, int tid){
  u64 c = P[tid];
  if (tid & 1) return c & ((c<<1)|(P[tid-1]>>63)) & ((c>>1)|(1ull<<63));
  else         return c & ((c<<1)|1ull) & ((c>>1)|(P[tid+1]<<63));
}
__device__ __forceinline__ u64 bdilate_x(const u64* P, int tid){
  u64 c = P[tid];
  if (tid & 1) return c | (c<<1) | (P[tid-1]>>63) | (c>>1);
  else         return c | (c<<1) | (c>>1) | (P[tid+1]<<63);
}

template<bool INIT>
__global__ __launch_bounds__(256) void bskel(const u64* __restrict__ imgin, u64* __restrict__ imgout,
                                             u64* __restrict__ skel)
{
  __shared__ u64 simg[4][256];
  __shared__ u64 se1[6][256];
  __shared__ u64 se2[2][256];
  __shared__ u64 sM[4][256];
  int bid = blockIdx.x;
  int tzb = bid & 31, b = (bid>>5)&1, m = bid>>6;
  int z0 = tzb*2, z1 = z0+2;
  size_t base = (size_t)m*NWORDS + (size_t)b*16384;
  const u64* vin = imgin + base;
  u64* vout = imgout + base;
  u64* skl = skel + base;
  int tid = threadIdx.x;
  int y = tid>>1;

  for (int s = z0-3; s <= z1+6; ++s){
    if (s <= z1+2)
      simg[(s+96)&3][tid] = ((unsigned)s<64u) ? vin[(s<<8)+tid] : ~0ull;
    { int t = s-2;
      if (t >= z0-2 && t <= z1+1){
        u64 r = ~0ull;
        if ((unsigned)t<64u){
          const u64* P = simg[(t+96)&3];
          if (INIT) r = P[tid];
          else {
            r = berode_x(P, tid);
            if(y>0)   r &= P[tid-2];
            if(y<127) r &= P[tid+2];
            r &= simg[(t-1+96)&3][tid] & simg[(t+1+96)&3][tid];
          }
        }
        se1[(t+96)%6][tid] = r;
      }
    }
    { int t = s-4;
      if (t >= z0-1 && t <= z1){
        u64 r = 0;
        if ((unsigned)t<64u){
          const u64* P = se1[(t+96)%6];
          r = berode_x(P, tid);
          if(y>0)   r &= P[tid-2];
          if(y<127) r &= P[tid+2];
          r &= se1[(t-1+96)%6][tid] & se1[(t+1+96)%6][tid];
        }
        se2[(t+96)&1][tid] = r;
      }
    }
    { int t = s-5;
      if (t >= z0-1 && t <= z1){
        const u64* P = se2[(t+96)&1];
        u64 dm = bdilate_x(P, tid);
        if(y>0)   dm |= bdilate_x(P, tid-2);
        if(y<127) dm |= bdilate_x(P, tid+2);
        sM[(t+96)&3][tid] = dm;
      }
    }
    { int z = s-7;
      if (z >= z0 && z < z1){
        u64 open_ = sM[(z-1+96)&3][tid] | sM[(z+96)&3][tid] | sM[(z+1+96)&3][tid];
        u64 e1v = se1[(z+96)%6][tid];
        u64 d = e1v & ~open_;
        int gw = (z<<8)+tid;
        if (INIT) skl[gw] = d;
        else { skl[gw] |= d; vout[gw] = e1v; }
      }
    }
    __syncthreads();
  }
}

// ---------------- separable Chebyshev EDT ----------------
__global__ __launch_bounds__(256) void edt_px(const u64* __restrict__ yb, const u64* __restrict__ hb,
                                              u8* __restrict__ d)
{
  int g = blockIdx.x*256 + threadIdx.x;
  int m = g >> 21;
  int n = g & (NTOT-1);
  const u64* bits = m ? hb : yb;
  int x = n & 127;
  int row = n >> 7;
  u64 w0 = bits[row*2], w1 = bits[row*2+1];
  int a = x - 31;
  u64 win;
  if (a < 0)        win = w0 << (-a);
  else if (a == 0)  win = w0;
  else if (a < 64)  win = (w0 >> a) | (w1 << (64-a));
  else              win = w1 >> (a-64);
  if (x < 31)  win |= (1ull << (31-x)) - 1;
  if (x > 95)  win |= (~0ull) << (159-x);
  u64 inv = ~win;
  u64 tl = inv & 0xFFFFFFFFull;
  u64 tr = inv >> 31;
  int dl = tl ? (31 - (63 - __clzll(tl))) : 99;
  int dr = tr ? (__ffsll((unsigned long long)tr) - 1) : 99;
  d[(size_t)g] = (u8)min(min(dl, dr), 16);
}

__global__ __launch_bounds__(256) void edt_py(const u8* __restrict__ din, u8* __restrict__ dout){
  int g = blockIdx.x*256 + threadIdx.x;
  int n = g & (NTOT-1);
  int c = (n >> 7) & 127;
  size_t idx = (size_t)g;
  int best = din[idx];
  #pragma unroll 4
  for (int k=1; k<=16; ++k){
    if (best <= k) break;
    int v = 255;
    if (c-k >= 0)   v = din[idx - (size_t)k*128];
    if (c+k < 128)  v = min(v, (int)din[idx + (size_t)k*128]);
    best = min(best, max(k, v));
  }
  dout[idx] = (u8)best;
}

// z-pass + per-block skeleton-radius max/min partials
__global__ __launch_bounds__(256) void edt_pz_part(const u8* __restrict__ din, u8* __restrict__ dout,
    const u64* __restrict__ skel2, const u64* __restrict__ hbits,
    u8* __restrict__ pmax, u8* __restrict__ pmin)
{
  int tid = threadIdx.x;
  int g = blockIdx.x*256 + tid;
  int m = g >> 21;
  int n = g & (NTOT-1);
  int c = (n >> 14) & 63;
  size_t idx = (size_t)g;
  int best = din[idx];
  #pragma unroll 4
  for (int k=1; k<=16; ++k){
    if (best <= k) break;
    int v = 255;
    if (c-k >= 0)  v = din[idx - (size_t)k*16384];
    if (c+k < 64)  v = min(v, (int)din[idx + (size_t)k*16384]);
    best = min(best, max(k, v));
  }
  dout[idx] = (u8)best;
  int wi = n>>6, bit = n&63;
  u64 sbit = m ? (skel2[NWORDS+wi] & hbits[wi]) : skel2[wi];
  u32 r = (u32)((sbit>>bit)&1ull) ? (u32)best : 0u;
  __shared__ u32 sx[256], sn_[256];
  sx[tid]=r; sn_[tid]=r;
  __syncthreads();
  for(int s=128;s>0;s>>=1){
    if(tid<s){
      if(sx[tid+s]>sx[tid]) sx[tid]=sx[tid+s];
      if(sn_[tid+s]<sn_[tid]) sn_[tid]=sn_[tid+s];
    }
    __syncthreads();
  }
  if(tid==0){ pmax[blockIdx.x]=(u8)sx[0]; pmin[blockIdx.x]=(u8)sn_[0]; }
}

// reduce 16384 block partials -> mm[8]
__global__ __launch_bounds__(256) void rmm2(const u8* __restrict__ pmax, const u8* __restrict__ pmin,
                                            u32* __restrict__ mm){
  __shared__ u8 smx[4][256], smn[4][256];
  int tid = threadIdx.x;
  u8 mx[4]={0,0,0,0}, mn[4]={255,255,255,255};
  for(int i=tid;i<16384;i+=256){
    int sel=i>>13, b=(i>>12)&1, cc=sel*2+b;
    u8 a=pmax[i], d=pmin[i];
    if(a>mx[cc]) mx[cc]=a;
    if(d<mn[cc]) mn[cc]=d;
  }
  #pragma unroll
  for(int cc=0;cc<4;cc++){ smx[cc][tid]=mx[cc]; smn[cc][tid]=mn[cc]; }
  __syncthreads();
  for(int s=128;s>0;s>>=1){
    if(tid<s){
      #pragma unroll
      for(int cc=0;cc<4;cc++){
        if(smx[cc][tid+s]>smx[cc][tid]) smx[cc][tid]=smx[cc][tid+s];
        if(smn[cc][tid+s]<smn[cc][tid]) smn[cc][tid]=smn[cc][tid+s];
      }
    }
    __syncthreads();
  }
  if(tid==0){
    #pragma unroll
    for(int cc=0;cc<4;cc++){
      int sel=cc>>1, b=cc&1;
      mm[sel*4+b]   = (u32)smx[cc][0];
      mm[sel*4+2+b] = (u32)smn[cc][0];
    }
  }
}

// ---------------- fused sobel + final reduce, 4 voxels per thread ----------------
__global__ __launch_bounds__(256) void k_tail(const float* __restrict__ net, const u16* __restrict__ skelp,
    const u64* __restrict__ ybits, const u64* __restrict__ hbits, const u64* __restrict__ skel2,
    const u8* __restrict__ acc, const u8* __restrict__ y8, const u32* __restrict__ mm,
    double* __restrict__ part1)
{
  float rmaxT_[2], rminT_[2], rmaxH_[2], rminH_[2];
  for(int b=0;b<2;b++){
    rmaxT_[b]=fmaxf((float)mm[b],1.f);   rminT_[b]=fmaxf((float)mm[2+b],1.f);
    rmaxH_[b]=fmaxf((float)mm[4+b],1.f); rminH_[b]=fmaxf((float)mm[6+b],1.f);
  }
  const int SMi[3]={1,2,1}, DVi[3]={-1,0,1};
  int r = blockIdx.x*256 + threadIdx.x;   // exactly NTOT/4 threads
  int n0 = r<<2;
  int b = n0>>20, v0 = n0&(VOL-1);
  int xb = n0&127, y=(n0>>7)&127, z=(n0>>14)&63;
  const float* P = net + (size_t)b*(2*VOL);
  const u8* Y8 = y8 + ((size_t)b<<20);
  float gpx[4]={0,0,0,0}, gpy[4]={0,0,0,0}, gpz[4]={0,0,0,0};
  int   gtx[4]={0,0,0,0}, gty[4]={0,0,0,0}, gtz[4]={0,0,0,0};
  #pragma unroll
  for(int da=0;da<3;da++){
    int zz=z+da-1; if((unsigned)zz>=64u) continue;
    #pragma unroll
    for(int db=0;db<3;db++){
      int yy=y+db-1; if((unsigned)yy>=128u) continue;
      int rb_ = (zz<<14)+(yy<<7)+xb;
      float pv[6]; int tv[6];
      #pragma unroll
      for(int j=0;j<6;j++){
        int xx = xb-1+j;
        bool ok = (unsigned)xx<128u;
        pv[j] = ok ? P[rb_-1+j] : 0.f;
        tv[j] = ok ? (int)Y8[rb_-1+j] : 0;
      }
      int smb=SMi[db], sma=SMi[da], dva=DVi[da];
      #pragma unroll
      for(int e=0;e<4;e++){
        float ep = pv[e+2]-pv[e], sp = pv[e]+2.f*pv[e+1]+pv[e+2];
        gpx[e] += (float)smb*ep; gpy[e] += (float)sma*ep; gpz[e] += (float)dva*sp;
        int et = tv[e+2]-tv[e], st = tv[e]+2*tv[e+1]+tv[e+2];
        gtx[e] += smb*et; gty[e] += sma*et; gtz[e] += dva*st;
      }
    }
  }
  float4 X0 = *(const float4*)&P[v0];
  float4 X1 = *(const float4*)&P[VOL+v0];
  ushort4 SK = *(const ushort4*)&skelp[n0];
  uchar4 DT = *(const uchar4*)&acc[n0];
  uchar4 DH = *(const uchar4*)&acc[NTOT+n0];
  int wi0 = n0>>6, bit0 = n0&63;
  int ybq = (int)((ybits[wi0]>>bit0)&0xFull);
  int hdq = (int)((hbits[wi0]>>bit0)&0xFull);
  int sTq = (int)((skel2[wi0]>>bit0)&0xFull);
  int sHq = (int)((skel2[NWORDS+wi0]>>bit0)&0xFull);
  float fsob=0,fcl1=0,fcl2=0,fcl3=0,fcl4=0,fi1=0,fun1=0,fi2=0,fun2=0;
  #pragma unroll
  for(int e=0;e<4;e++){
    float ftx=(float)gtx[e], fty=(float)gty[e], ftz=(float)gtz[e];
    float np_=sqrtf(gpx[e]*gpx[e]+gpy[e]*gpy[e]+gpz[e]*gpz[e]);
    float nt_=sqrtf(ftx*ftx+fty*fty+ftz*ftz);
    float ip=1.f/fmaxf(np_,1e-12f), it=1.f/fmaxf(nt_,1e-12f);
    float num=(gpx[e]*ftx+gpy[e]*fty+gpz[e]*ftz)*ip*it;
    float den=fmaxf((np_*ip)*(nt_*it),1e-8f);
    fsob += num/den;
    int yb=(ybq>>e)&1, hd=(hdq>>e)&1, sT=(sTq>>e)&1, sH=(sHq>>e)&1;
    float dT=(float)((const u8*)&DT)[e], dH=(float)((const u8*)&DH)[e];
    float x0v=((const float*)&X0)[e], x1v=((const float*)&X1)[e];
    float p = 1.f/(1.f+__expf(x0v-x1v));
    float sk = h2f(((const u16*)&SK)[e]);
    fcl1 += sk*(float)yb;
    fcl2 += sk;
    float q_vl = yb ? fminf(dT,rmaxT_[b])/rmaxT_[b] : 0.f;
    if (sT){
      fcl3 += p; fcl4 += 1.f;
      float t=(rmaxT_[b]-dT+rminT_[b])/rmaxT_[b]; float q_sl=t*t;
      float q_vp = fminf(dH,rmaxH_[b])/rmaxH_[b]*p;
      fi2  += q_sl*__powf(q_vp+1e-4f,0.7f)*q_sl;
      fun2 += q_sl*(0.1f*q_vp+0.9f*q_sl);
    }
    if (sH & hd){
      float t=(rmaxH_[b]-dH+rminH_[b])/rmaxH_[b]; float q_sp=t*t*p;
      fi1  += q_sp*__powf(q_sp+1e-4f,0.7f)*q_vl;
      fun1 += q_sp*(0.1f*q_sp+0.9f*q_vl);
    }
  }
  __shared__ double sw[9][4];
  int wid = threadIdx.x>>6, lane = threadIdx.x&63;
  double vals[9] = {fsob,fcl1,fcl2,fcl3,fcl4,fi1,fun1,fi2,fun2};
  #pragma unroll
  for(int s=0;s<9;s++){ double rr = wred(vals[s]); if(lane==0) sw[s][wid]=rr; }
  __syncthreads();
  if(threadIdx.x==0){
    #pragma unroll
    for(int s=0;s<9;s++) part1[(size_t)s*PC1 + blockIdx.x] = sw[s][0]+sw[s][1]+sw[s][2]+sw[s][3];
  }
}

// ---------------- two-stage finalize ----------------
__global__ __launch_bounds__(256) void k_reduce_mid(const double* __restrict__ part0,
                                                    const double* __restrict__ part1,
                                                    double* __restrict__ tot){
  int s = blockIdx.x;  // 0..13
  const double* src; int n;
  if (s < 5){ src = part0 + (size_t)s*PC0; n = PC0; }
  else      { src = part1 + (size_t)(s-5)*PC1; n = PC1; }
  double v=0;
  for(int i=threadIdx.x;i<n;i+=256) v += src[i];
  __shared__ double sd[256];
  sd[threadIdx.x]=v; __syncthreads();
  for(int k=128;k>0;k>>=1){ if((int)threadIdx.x<k) sd[threadIdx.x]+=sd[threadIdx.x+k]; __syncthreads(); }
  if(threadIdx.x==0) tot[s]=sd[0];
}

__global__ void k_fin(const double* __restrict__ tot, float* __restrict__ out){
  if(threadIdx.x==0 && blockIdx.x==0){
    const double N = (double)NTOT;
    double ce = tot[0]/N;
    double tp=tot[1], fp=tot[2]-tot[1], fn=tot[3]-tot[1];
    double dice = -((2.0*tp+1e-5)/(2.0*tp+fp+fn+1e-5));
    double conn = tot[4]/(2.0*N);
    double dir  = 1.0 - tot[5]/N;
    double tprec = (tot[6]+1.0)/(tot[7]+1.0);
    double tsens = (tot[8]+1.0)/(tot[9]+1.0);
    double cld = 1.0 - 2.0*tprec*tsens/(tprec+tsens);
    double u1 = 1.0 - (tot[10]+1.0)/(tot[11]+1.0);
    double u2 = 1.0 - (tot[12]+1.0)/(tot[13]+1.0);
    out[0] = (float)(dice+ce+cld+dir+conn+u1+u2);
  }
}

extern "C" void kernel_launch(void* const* d_in, const int* in_sizes, int n_in,
                              void* d_out, int out_size, void* d_ws, size_t ws_size,
                              hipStream_t stream)
{
  (void)in_sizes; (void)n_in; (void)out_size; (void)ws_size;
  const float* net = (const float*)d_in[0];
  const int*   tgt = (const int*)d_in[1];
  float* out = (float*)d_out;
  char* w = (char*)d_ws;
  const size_t MB = 1024*1024;
  u16* F1 = (u16*)(w + 0*MB);              // prob img ping (fp16)
  u16* F2 = (u16*)(w + 4*MB);              // skel_pred (fp16)
  u16* F3 = (u16*)(w + 8*MB);              // img pong (fp16)
  u64* ybits = (u64*)(w + 12*MB);
  u64* hbits = ybits + NWORDS;
  u64* skel2 = hbits + NWORDS;             // [T][H]
  u64* bping = skel2 + 2*NWORDS;           // [T][H]
  u64* bpong = bping + 2*NWORDS;
  u8*  dA    = (u8*)(bpong + 2*NWORDS);    // 4 MB
  u8*  dB    = dA + (size_t)2*NTOT;        // 4 MB
  u8*  y8    = dB + (size_t)2*NTOT;        // 2 MB
  double* part0 = (double*)(y8 + (size_t)NTOT);
  double* part1 = part0 + (size_t)5*PC0;
  double* tot   = part1 + (size_t)9*PC1;
  u8* pmax = (u8*)(tot + 16);
  u8* pmin = pmax + 16384;
  u32* mm  = (u32*)(pmin + 16384);

  k_init<<<PC0, 256, 0, stream>>>(net, tgt, F1, ybits, hbits, bping, y8, part0);

  // binary soft_skel for y_true and hard: 11 systolic dispatches (128 blocks each)
  bskel<true><<<128,256,0,stream>>>(bping, bpong, skel2);
  {
    u64* pi=bping; u64* po=bpong;
    for(int i=0;i<10;i++){ bskel<false><<<128,256,0,stream>>>(pi,po,skel2); u64* t=pi; pi=po; po=t; }
  }

  // float soft_skel(prob, 10) = 11 d-terms: 5 double-step dispatches + 1 single
  fskel2<true><<<2048,256,0,stream>>>(F1, F3, F2, 1);    // d0,d1 ; writes E_2
  fskel2<false><<<2048,256,0,stream>>>(F3, F1, F2, 1);   // d2,d3 ; E_4
  fskel2<false><<<2048,256,0,stream>>>(F1, F3, F2, 1);   // d4,d5 ; E_6
  fskel2<false><<<2048,256,0,stream>>>(F3, F1, F2, 1);   // d6,d7 ; E_8
  fskel2<false><<<2048,256,0,stream>>>(F1, F3, F2, 1);   // d8,d9 ; E_10
  fskel1<<<2048,256,0,stream>>>(F3, F2);                 // d10 (no img write)

  // separable Chebyshev EDT (+ fused skeleton-radius partials in z-pass)
  const int GE = (2*NTOT)/256;
  edt_px<<<GE,256,0,stream>>>(ybits, hbits, dA);
  edt_py<<<GE,256,0,stream>>>(dA, dB);
  edt_pz_part<<<GE,256,0,stream>>>(dB, dA, skel2, hbits, pmax, pmin);
  rmm2<<<1,256,0,stream>>>(pmax, pmin, mm);

  k_tail<<<PC1,256,0,stream>>>(net, F2, ybits, hbits, skel2, dA, y8, mm, part1);
  k_reduce_mid<<<14,256,0,stream>>>(part0, part1, tot);
  k_fin<<<1,64,0,stream>>>(tot, out);
}

// Round 10
// 342.173 us; speedup vs baseline: 1.6426x; 1.1076x over previous
//
#include <hip/hip_runtime.h>
#include <math.h>

typedef unsigned long long u64;
typedef unsigned int u32;
typedef unsigned short u16;
typedef unsigned char u8;

#define VOL 1048576              // 64*128*128
#define NTOT 2097152             // 2 batches
#define NWORDS 32768             // NTOT/64
#define PC0 8192
#define PC1 2048

union HU { u16 u; _Float16 h; };
__device__ __forceinline__ float h2f(u16 u){ HU x; x.u=u; return (float)x.h; }
__device__ __forceinline__ u16 f2h(float f){ HU x; x.h=(_Float16)f; return x.u; }
#define H_ONE2 0x3C003C00u   // pair of 1.0 (erode-neutral)

// packed fp16 min/max (2 voxels per op)
__device__ __forceinline__ u32 pmin(u32 a, u32 b){ u32 r; asm("v_pk_min_f16 %0, %1, %2" : "=v"(r) : "v"(a), "v"(b)); return r; }
__device__ __forceinline__ u32 pmax(u32 a, u32 b){ u32 r; asm("v_pk_max_f16 %0, %1, %2" : "=v"(r) : "v"(a), "v"(b)); return r; }

__device__ __forceinline__ double wred(double v){
  #pragma unroll
  for(int o=32;o;o>>=1) v += __shfl_down(v, o);
  return v;
}

// ---------------- init: prob(fp16), bitmasks, dice/ce/conn sums ----------------
__global__ __launch_bounds__(256) void k_init(const float* __restrict__ net, const int* __restrict__ tgt,
    u16* __restrict__ img, u64* __restrict__ ybits, u64* __restrict__ hbits,
    u64* __restrict__ bimg2, double* __restrict__ part)
{
  int n = blockIdx.x*256 + threadIdx.x;
  int b = n >> 20;
  int v = n & (VOL-1);
  const float* nb = net + (size_t)b*(2*VOL);
  float x0 = nb[v], x1 = nb[VOL+v];
  int t = tgt[n];
  int yb = (t>0) ? 1 : 0;
  float p = 1.f/(1.f+__expf(x0-x1));
  img[n] = f2h(p);
  u64 wy = __ballot(yb);
  u64 wh = __ballot(x1 > x0);
  if((threadIdx.x & 63)==0){
    int wi = n>>6;
    ybits[wi]=wy; hbits[wi]=wh;
    bimg2[wi]=wy; bimg2[NWORDS+wi]=wh;
  }
  float mx = fmaxf(x0,x1);
  float lse = mx + __logf(__expf(x0-mx)+__expf(x1-mx));
  double ce = (double)(lse - (yb ? x1 : x0));
  double tp = (double)p * yb;
  double spr = (double)p;
  double sy = (double)yb;
  double conn = (double)((int)((x0>0.5f)!=(yb!=0)) + (int)((x1>0.5f)!=(yb!=0)));
  __shared__ double sw[5][4];
  int wid = threadIdx.x>>6, lane = threadIdx.x&63;
  double vals[5] = {ce,tp,spr,sy,conn};
  #pragma unroll
  for(int s=0;s<5;s++){ double r = wred(vals[s]); if(lane==0) sw[s][wid]=r; }
  __syncthreads();
  if(threadIdx.x==0){
    #pragma unroll
    for(int s=0;s<5;s++) part[(size_t)s*PC0 + blockIdx.x] = sw[s][0]+sw[s][1]+sw[s][2]+sw[s][3];
  }
}

// ---------------- fskel2p: TWO soft-skel iterations, x-pair packed fp16 ----------------
// tile 32x8x4, 2048 blocks. A=E_k halo3 [10][14][20]pairs(base x=X0-4), B=E_{k+1} halo2
// [8][12][18](base X0-2, OOB->1.0), C=E_{k+2} halo1 [6][10][18](base X0-2, OOB->0).
// X1/X2 [6][10][16] reuse A; Y1/Y2 [6][8][16] reuse B. 5 barriers.
template<bool INIT>
__global__ __launch_bounds__(256) void fskel2(const u16* __restrict__ imgin, u16* __restrict__ imgout,
                                              u16* __restrict__ skel)
{
  __shared__ u32 A_[2800];
  __shared__ u32 B_[1728];
  __shared__ u32 C_[1080];
  int bid = blockIdx.x;
  int xb = bid&3, yb=(bid>>2)&15, zb=(bid>>6)&15, b=bid>>10;
  int X0=xb*32, Y0=yb*8, Z0=zb*4;
  const u32* vin = (const u32*)(imgin + (size_t)b*VOL);
  u32* vout = (u32*)(imgout + (size_t)b*VOL);
  u32* skl = (u32*)(skel + (size_t)b*VOL);
  int tid = threadIdx.x;

  // P0: load A (pairs), OOB -> 1.0
  {
    int y0 = tid/20, x0 = tid - y0*20;
    int gy0 = Y0-3+y0, gx0 = X0-4+2*x0;
    bool ok0 = ((unsigned)gy0<128u) & ((unsigned)gx0<128u);
    int gb0 = (gy0<<6)+(gx0>>1);
    int t1 = tid+256; int y1 = t1/20, x1 = t1-y1*20;
    int gy1 = Y0-3+y1, gx1 = X0-4+2*x1;
    bool hv1 = tid<24;
    bool ok1 = ((unsigned)gy1<128u) & ((unsigned)gx1<128u);
    int gb1 = (gy1<<6)+(gx1>>1);
    #pragma unroll
    for(int z=0; z<10; ++z){
      int gz = Z0-3+z;
      bool zok = (unsigned)gz<64u;
      int zb2 = gz<<13;
      A_[z*280+tid] = (zok&ok0) ? vin[zb2+gb0] : H_ONE2;
      if (hv1) A_[z*280+t1] = (zok&ok1) ? vin[zb2+gb1] : H_ONE2;
    }
  }
  __syncthreads();
  // P1: B = erode7(A), OOB word -> 1.0
  if (tid < 216){
    int y = tid/18, px = tid - y*18;
    int gy = Y0-2+y;
    bool yok = (unsigned)gy<128u;
    bool xout = ((X0==0)&&(px==0)) || ((X0==96)&&(px==17));
    #pragma unroll
    for(int z=0; z<8; ++z){
      bool zok = (unsigned)(Z0-2+z)<64u;
      u32 v = H_ONE2;
      if (zok && yok && !xout){
        int c = (z+1)*280 + (y+1)*20 + (px+1);
        u32 C0=A_[c], L=A_[c-1], R=A_[c+1];
        u32 SL=(L>>16)|(C0<<16), SR=(C0>>16)|(R<<16);
        u32 m = pmin(pmin(SL,SR), C0);
        m = pmin(m, pmin(A_[c-20],A_[c+20]));
        v = pmin(m, pmin(A_[c-280],A_[c+280]));
      }
      B_[z*216+tid] = v;
    }
  }
  __syncthreads();
  // P2: C = erode7(B), OOB word -> 0; write E_{k+2} center to global
  if (tid < 180){
    int y = tid/18, px = tid - y*18;
    int gy = Y0-1+y;
    bool yok = (unsigned)gy<128u;
    bool xout = ((X0==0)&&(px==0)) || ((X0==96)&&(px==17));
    bool ctr = (px>=1)&&(px<=16)&&(y>=1)&&(y<=8);
    int pxm = (px>0)? px-1 : 0;
    int pxp = (px<17)? px+1 : 17;
    int gb = (gy<<6)+((X0-2+2*px)>>1);
    #pragma unroll
    for(int z=0; z<6; ++z){
      int gz = Z0-1+z;
      bool zok = (unsigned)gz<64u;
      u32 v = 0;
      if (zok && yok && !xout){
        int c = (z+1)*216 + (y+1)*18;
        u32 C0=B_[c+px], L=B_[c+pxm], R=B_[c+pxp];
        u32 SL=(L>>16)|(C0<<16), SR=(C0>>16)|(R<<16);
        u32 m = pmin(pmin(SL,SR), C0);
        m = pmin(m, pmin(B_[c+px-18],B_[c+px+18]));
        v = pmin(m, pmin(B_[c-216+px],B_[c+216+px]));
      }
      C_[z*180+tid] = v;
      if (ctr && z>=1 && z<=4)
        vout[(gz<<13)+gb] = v;
    }
  }
  // snapshots (reads A,B only; P2 wrote C — no race)
  int col = tid>>1, zh = tid&1;
  int oy = col>>4, opx = col&15;
  u32 ek0[2], ek1[2];
  #pragma unroll
  for(int j=0;j<2;j++){
    int z = zh*2+j;
    ek0[j] = A_[(z+3)*280+(oy+3)*20+(opx+2)];
    ek1[j] = B_[(z+2)*216+(oy+2)*18+(opx+1)];
  }
  __syncthreads();
  // P3: X1 = xmax(B) (masked), X2 = xmax(C) -> A space
  u32* X1 = A_; u32* X2 = A_ + 960;
  if (tid < 160){
    int y = tid>>4, px = tid&15;
    int px1 = px+1;
    int gy = Y0-1+y;
    bool yok = (unsigned)gy<128u;
    bool mlo = (X0==0)&&(px==0);
    bool mhi = (X0==96)&&(px==15);
    #pragma unroll
    for(int z=0; z<6; ++z){
      bool zok = (unsigned)(Z0-1+z)<64u;
      {
        int c = (z+1)*216 + (y+1)*18 + px1;
        u32 C0=B_[c], L=B_[c-1], R=B_[c+1];
        if (mlo) L = 0;
        if (mhi) R = 0;
        u32 SL=(L>>16)|(C0<<16), SR=(C0>>16)|(R<<16);
        u32 v = pmax(pmax(SL,SR), C0);
        X1[z*160+tid] = (zok&&yok) ? v : 0;
      }
      {
        int c = z*180 + y*18 + px1;
        u32 C0=C_[c], L=C_[c-1], R=C_[c+1];
        u32 SL=(L>>16)|(C0<<16), SR=(C0>>16)|(R<<16);
        X2[z*160+tid] = pmax(pmax(SL,SR), C0);
      }
    }
  }
  __syncthreads();
  // P4: Y = ymax(X) -> B space
  u32* Y1 = B_; u32* Y2 = B_ + 768;
  {
    int arr = tid>>7, rem = tid&127;
    int y = rem>>4, px = rem&15;
    const u32* Xs = arr ? X2 : X1;
    u32* Ys = arr ? Y2 : Y1;
    #pragma unroll
    for(int z=0; z<6; ++z){
      int c = z*160 + y*16 + px;
      Ys[z*128 + rem] = pmax(pmax(Xs[c], Xs[c+16]), Xs[c+32]);
    }
  }
  __syncthreads();
  // P5: zmax + two skel updates
  {
    int gx = X0 + 2*opx;
    #pragma unroll
    for(int j=0;j<2;j++){
      int z = zh*2+j;
      int gz = Z0+z;
      int c = z*128 + oy*16 + opx;
      u32 o1 = pmax(pmax(Y1[c], Y1[c+128]), Y1[c+256]);
      u32 o2 = pmax(pmax(Y2[c], Y2[c+128]), Y2[c+256]);
      u32 idx = (u32)((gz<<13) + ((Y0+oy)<<6) + (gx>>1));
      float d0l = fmaxf(h2f((u16)ek0[j]) - h2f((u16)o1), 0.f);
      float d0h = fmaxf(h2f((u16)(ek0[j]>>16)) - h2f((u16)(o1>>16)), 0.f);
      float d1l = fmaxf(h2f((u16)ek1[j]) - h2f((u16)o2), 0.f);
      float d1h = fmaxf(h2f((u16)(ek1[j]>>16)) - h2f((u16)(o2>>16)), 0.f);
      float sl_, sh_;
      if (INIT){ sl_ = d0l; sh_ = d0h; }
      else {
        u32 swv = skl[idx];
        sl_ = h2f((u16)swv); sh_ = h2f((u16)(swv>>16));
        sl_ += fmaxf(d0l - sl_*d0l, 0.f); sh_ += fmaxf(d0h - sh_*d0h, 0.f);
      }
      sl_ += fmaxf(d1l - sl_*d1l, 0.f); sh_ += fmaxf(d1h - sh_*d1h, 0.f);
      skl[idx] = (u32)f2h(sl_) | ((u32)f2h(sh_)<<16);
    }
  }
}

// ---------------- fskel1p: single iteration (last d-term), packed ----------------
__global__ __launch_bounds__(256) void fskel1(const u16* __restrict__ imgin, u16* __restrict__ skel)
{
  __shared__ u32 A2[1920];   // E_k halo2 [8][12][20] base X0-4; reused as X [6][10][16]
  __shared__ u32 B2[1080];   // E_{k+1} halo1 [6][10][18] base X0-2, OOB->0; reused as Y [6][8][16]
  int bid = blockIdx.x;
  int xb = bid&3, yb=(bid>>2)&15, zb=(bid>>6)&15, b=bid>>10;
  int X0=xb*32, Y0=yb*8, Z0=zb*4;
  const u32* vin = (const u32*)(imgin + (size_t)b*VOL);
  u32* skl = (u32*)(skel + (size_t)b*VOL);
  int tid = threadIdx.x;
  // P0: load A2, OOB -> 1.0
  if (tid < 240){
    int y0 = tid/20, x0 = tid - y0*20;
    int gy0 = Y0-2+y0, gx0 = X0-4+2*x0;
    bool ok0 = ((unsigned)gy0<128u) & ((unsigned)gx0<128u);
    int gb0 = (gy0<<6)+(gx0>>1);
    #pragma unroll
    for(int z=0; z<8; ++z){
      int gz = Z0-2+z;
      bool zok = (unsigned)gz<64u;
      A2[z*240+tid] = (zok&ok0) ? vin[(gz<<13)+gb0] : H_ONE2;
    }
  }
  __syncthreads();
  // P1: B2 = erode7(A2), OOB -> 0
  if (tid < 180){
    int y = tid/18, px = tid - y*18;
    int gy = Y0-1+y;
    bool yok = (unsigned)gy<128u;
    bool xout = ((X0==0)&&(px==0)) || ((X0==96)&&(px==17));
    int pxm = (px>0)? px-1 : 0;
    int pxp = (px<17)? px+1 : 17;
    #pragma unroll
    for(int z=0; z<6; ++z){
      bool zok = (unsigned)(Z0-1+z)<64u;
      u32 v = 0;
      if (zok && yok && !xout){
        int c = (z+1)*240 + (y+1)*20;
        u32 C0=A2[c+px+1], L=A2[c+pxm+1], R=A2[c+pxp+1];
        u32 SL=(L>>16)|(C0<<16), SR=(C0>>16)|(R<<16);
        u32 m = pmin(pmin(SL,SR), C0);
        m = pmin(m, pmin(A2[c+px+1-20],A2[c+px+1+20]));
        v = pmin(m, pmin(A2[c-240+px+1],A2[c+240+px+1]));
      }
      B2[z*180+tid] = v;
    }
  }
  int col = tid>>1, zh = tid&1;
  int oy = col>>4, opx = col&15;
  u32 ek[2];
  #pragma unroll
  for(int j=0;j<2;j++){
    int z = zh*2+j;
    ek[j] = A2[(z+2)*240+(oy+2)*20+(opx+2)];
  }
  __syncthreads();
  // P2: X = xmax(B2) -> A2 space (B2 already 0 at OOB)
  u32* X = A2;
  if (tid < 160){
    int y = tid>>4, px = tid&15;
    int px1 = px+1;
    #pragma unroll
    for(int z=0; z<6; ++z){
      int c = z*180 + y*18 + px1;
      u32 C0=B2[c], L=B2[c-1], R=B2[c+1];
      u32 SL=(L>>16)|(C0<<16), SR=(C0>>16)|(R<<16);
      X[z*160+tid] = pmax(pmax(SL,SR), C0);
    }
  }
  __syncthreads();
  // P3: Y = ymax(X) -> B2 space
  u32* Y = B2;
  if (tid < 128){
    int y = tid>>4, px = tid&15;
    #pragma unroll
    for(int z=0; z<6; ++z){
      int c = z*160 + y*16 + px;
      Y[z*128 + tid] = pmax(pmax(X[c], X[c+16]), X[c+32]);
    }
  }
  __syncthreads();
  // P4: zmax + skel update
  {
    int gx = X0 + 2*opx;
    #pragma unroll
    for(int j=0;j<2;j++){
      int z = zh*2+j;
      int gz = Z0+z;
      int c = z*128 + oy*16 + opx;
      u32 o = pmax(pmax(Y[c], Y[c+128]), Y[c+256]);
      u32 idx = (u32)((gz<<13) + ((Y0+oy)<<6) + (gx>>1));
      float dl = fmaxf(h2f((u16)ek[j]) - h2f((u16)o), 0.f);
      float dh = fmaxf(h2f((u16)(ek[j]>>16)) - h2f((u16)(o>>16)), 0.f);
      u32 swv = skl[idx];
      float sl_ = h2f((u16)swv), sh_ = h2f((u16)(swv>>16));
      sl_ += fmaxf(dl - sl_*dl, 0.f); sh_ += fmaxf(dh - sh_*dh, 0.f);
      skl[idx] = (u32)f2h(sl_) | ((u32)f2h(sh_)<<16);
    }
  }
}

// ---------------- systolic binary soft-skel iteration (bit-planes), chunk 2 ----------------
__device__ __forceinline__ u64 berode_x(const u64* P, int tid){
  u64 c = P[tid];
  if (tid & 1) return c & ((c<<1)|(P[tid-1]>>63)) & ((c>>1)|(1ull<<63));
  else         return c & ((c<<1)|1ull) & ((c>>1)|(P[tid+1]<<63));
}
__device__ __forceinline__ u64 bdilate_x(const u64* P, int tid){
  u64 c = P[tid];
  if (tid & 1) return c | (c<<1) | (P[tid-1]>>63) | (c>>1);
  else         return c | (c<<1) | (c>>1) | (P[tid+1]<<63);
}

template<bool INIT>
__global__ __launch_bounds__(256) void bskel(const u64* __restrict__ imgin, u64* __restrict__ imgout,
                                             u64* __restrict__ skel)
{
  __shared__ u64 simg[4][256];
  __shared__ u64 se1[6][256];
  __shared__ u64 se2[2][256];
  __shared__ u64 sM[4][256];
  int bid = blockIdx.x;
  int tzb = bid & 31, b = (bid>>5)&1, m = bid>>6;
  int z0 = tzb*2, z1 = z0+2;
  size_t base = (size_t)m*NWORDS + (size_t)b*16384;
  const u64* vin = imgin + base;
  u64* vout = imgout + base;
  u64* skl = skel + base;
  int tid = threadIdx.x;
  int y = tid>>1;

  for (int s = z0-3; s <= z1+6; ++s){
    if (s <= z1+2)
      simg[(s+96)&3][tid] = ((unsigned)s<64u) ? vin[(s<<8)+tid] : ~0ull;
    { int t = s-2;
      if (t >= z0-2 && t <= z1+1){
        u64 r = ~0ull;
        if ((unsigned)t<64u){
          const u64* P = simg[(t+96)&3];
          if (INIT) r = P[tid];
          else {
            r = berode_x(P, tid);
            if(y>0)   r &= P[tid-2];
            if(y<127) r &= P[tid+2];
            r &= simg[(t-1+96)&3][tid] & simg[(t+1+96)&3][tid];
          }
        }
        se1[(t+96)%6][tid] = r;
      }
    }
    { int t = s-4;
      if (t >= z0-1 && t <= z1){
        u64 r = 0;
        if ((unsigned)t<64u){
          const u64* P = se1[(t+96)%6];
          r = berode_x(P, tid);
          if(y>0)   r &= P[tid-2];
          if(y<127) r &= P[tid+2];
          r &= se1[(t-1+96)%6][tid] & se1[(t+1+96)%6][tid];
        }
        se2[(t+96)&1][tid] = r;
      }
    }
    { int t = s-5;
      if (t >= z0-1 && t <= z1){
        const u64* P = se2[(t+96)&1];
        u64 dm = bdilate_x(P, tid);
        if(y>0)   dm |= bdilate_x(P, tid-2);
        if(y<127) dm |= bdilate_x(P, tid+2);
        sM[(t+96)&3][tid] = dm;
      }
    }
    { int z = s-7;
      if (z >= z0 && z < z1){
        u64 open_ = sM[(z-1+96)&3][tid] | sM[(z+96)&3][tid] | sM[(z+1+96)&3][tid];
        u64 e1v = se1[(z+96)%6][tid];
        u64 d = e1v & ~open_;
        int gw = (z<<8)+tid;
        if (INIT) skl[gw] = d;
        else { skl[gw] |= d; vout[gw] = e1v; }
      }
    }
    __syncthreads();
  }
}

// ---------------- separable Chebyshev EDT ----------------
__global__ __launch_bounds__(256) void edt_px(const u64* __restrict__ yb, const u64* __restrict__ hb,
                                              u8* __restrict__ d)
{
  int g = blockIdx.x*256 + threadIdx.x;
  int m = g >> 21;
  int n = g & (NTOT-1);
  const u64* bits = m ? hb : yb;
  int x = n & 127;
  int row = n >> 7;
  u64 w0 = bits[row*2], w1 = bits[row*2+1];
  int a = x - 31;
  u64 win;
  if (a < 0)        win = w0 << (-a);
  else if (a == 0)  win = w0;
  else if (a < 64)  win = (w0 >> a) | (w1 << (64-a));
  else              win = w1 >> (a-64);
  if (x < 31)  win |= (1ull << (31-x)) - 1;
  if (x > 95)  win |= (~0ull) << (159-x);
  u64 inv = ~win;
  u64 tl = inv & 0xFFFFFFFFull;
  u64 tr = inv >> 31;
  int dl = tl ? (31 - (63 - __clzll(tl))) : 99;
  int dr = tr ? (__ffsll((unsigned long long)tr) - 1) : 99;
  d[(size_t)g] = (u8)min(min(dl, dr), 16);
}

__global__ __launch_bounds__(256) void edt_py(const u8* __restrict__ din, u8* __restrict__ dout){
  int g = blockIdx.x*256 + threadIdx.x;
  int n = g & (NTOT-1);
  int c = (n >> 7) & 127;
  size_t idx = (size_t)g;
  int best = din[idx];
  #pragma unroll 4
  for (int k=1; k<=16; ++k){
    if (best <= k) break;
    int v = 255;
    if (c-k >= 0)   v = din[idx - (size_t)k*128];
    if (c+k < 128)  v = min(v, (int)din[idx + (size_t)k*128]);
    best = min(best, max(k, v));
  }
  dout[idx] = (u8)best;
}

__global__ __launch_bounds__(256) void edt_pz_part(const u8* __restrict__ din, u8* __restrict__ dout,
    const u64* __restrict__ skel2, const u64* __restrict__ hbits,
    u8* __restrict__ pmaxv, u8* __restrict__ pminv)
{
  int tid = threadIdx.x;
  int g = blockIdx.x*256 + tid;
  int m = g >> 21;
  int n = g & (NTOT-1);
  int c = (n >> 14) & 63;
  size_t idx = (size_t)g;
  int best = din[idx];
  #pragma unroll 4
  for (int k=1; k<=16; ++k){
    if (best <= k) break;
    int v = 255;
    if (c-k >= 0)  v = din[idx - (size_t)k*16384];
    if (c+k < 64)  v = min(v, (int)din[idx + (size_t)k*16384]);
    best = min(best, max(k, v));
  }
  dout[idx] = (u8)best;
  int wi = n>>6, bit = n&63;
  u64 sbit = m ? (skel2[NWORDS+wi] & hbits[wi]) : skel2[wi];
  u32 r = (u32)((sbit>>bit)&1ull) ? (u32)best : 0u;
  __shared__ u32 sx[256], sn_[256];
  sx[tid]=r; sn_[tid]=r;
  __syncthreads();
  for(int s=128;s>0;s>>=1){
    if(tid<s){
      if(sx[tid+s]>sx[tid]) sx[tid]=sx[tid+s];
      if(sn_[tid+s]<sn_[tid]) sn_[tid]=sn_[tid+s];
    }
    __syncthreads();
  }
  if(tid==0){ pmaxv[blockIdx.x]=(u8)sx[0]; pminv[blockIdx.x]=(u8)sn_[0]; }
}

__global__ __launch_bounds__(256) void rmm2(const u8* __restrict__ pmaxv, const u8* __restrict__ pminv,
                                            u32* __restrict__ mm){
  __shared__ u8 smx[4][256], smn[4][256];
  int tid = threadIdx.x;
  u8 mx[4]={0,0,0,0}, mn[4]={255,255,255,255};
  for(int i=tid;i<16384;i+=256){
    int sel=i>>13, b=(i>>12)&1, cc=sel*2+b;
    u8 a=pmaxv[i], d=pminv[i];
    if(a>mx[cc]) mx[cc]=a;
    if(d<mn[cc]) mn[cc]=d;
  }
  #pragma unroll
  for(int cc=0;cc<4;cc++){ smx[cc][tid]=mx[cc]; smn[cc][tid]=mn[cc]; }
  __syncthreads();
  for(int s=128;s>0;s>>=1){
    if(tid<s){
      #pragma unroll
      for(int cc=0;cc<4;cc++){
        if(smx[cc][tid+s]>smx[cc][tid]) smx[cc][tid]=smx[cc][tid+s];
        if(smn[cc][tid+s]<smn[cc][tid]) smn[cc][tid]=smn[cc][tid+s];
      }
    }
    __syncthreads();
  }
  if(tid==0){
    #pragma unroll
    for(int cc=0;cc<4;cc++){
      int sel=cc>>1, b=cc&1;
      mm[sel*4+b]   = (u32)smx[cc][0];
      mm[sel*4+2+b] = (u32)smn[cc][0];
    }
  }
}

// ---------------- fused sobel + final reduce, 4 voxels/thread, bit-based tv ----------------
__global__ __launch_bounds__(256) void k_tail(const float* __restrict__ net, const u16* __restrict__ skelp,
    const u64* __restrict__ ybits, const u64* __restrict__ hbits, const u64* __restrict__ skel2,
    const u8* __restrict__ acc, const u32* __restrict__ mm, double* __restrict__ part1)
{
  float rmaxT_[2], rminT_[2], rmaxH_[2], rminH_[2];
  for(int b=0;b<2;b++){
    rmaxT_[b]=fmaxf((float)mm[b],1.f);   rminT_[b]=fmaxf((float)mm[2+b],1.f);
    rmaxH_[b]=fmaxf((float)mm[4+b],1.f); rminH_[b]=fmaxf((float)mm[6+b],1.f);
  }
  const int SMi[3]={1,2,1}, DVi[3]={-1,0,1};
  int r = blockIdx.x*256 + threadIdx.x;
  int n0 = r<<2;
  int b = n0>>20, v0 = n0&(VOL-1);
  int xb = n0&127, y=(n0>>7)&127, z=(n0>>14)&63;
  const float* P = net + (size_t)b*(2*VOL);
  float gpx[4]={0,0,0,0}, gpy[4]={0,0,0,0}, gpz[4]={0,0,0,0};
  int   gtx[4]={0,0,0,0}, gty[4]={0,0,0,0}, gtz[4]={0,0,0,0};
  #pragma unroll
  for(int da=0;da<3;da++){
    int zz=z+da-1; if((unsigned)zz>=64u) continue;
    #pragma unroll
    for(int db=0;db<3;db++){
      int yy=y+db-1; if((unsigned)yy>=128u) continue;
      int rowoff = (zz<<14)+(yy<<7);
      const u64* yw = ybits + (size_t)(b<<14) + (rowoff>>6);
      u64 w0 = yw[0], w1 = yw[1];
      u32 win;
      if (xb == 0) win = (u32)((w0 & 0x1Full) << 1);
      else {
        int p = xb-1; int off = p & 63;
        u64 av = (p>=64) ? w1 : w0;
        u64 bv = (p>=64) ? 0ull : w1;
        win = (u32)((off ? ((av>>off) | (bv<<(64-off))) : av) & 0x3Full);
      }
      int rb_ = rowoff + xb;
      const float4 pc = *(const float4*)&P[rb_];
      float pva[6];
      pva[0] = (xb>0)   ? P[rb_-1] : 0.f;
      pva[1]=pc.x; pva[2]=pc.y; pva[3]=pc.z; pva[4]=pc.w;
      pva[5] = (xb<124) ? P[rb_+4] : 0.f;
      int smb=SMi[db], sma=SMi[da], dva=DVi[da];
      #pragma unroll
      for(int e=0;e<4;e++){
        float ep = pva[e+2]-pva[e], sp = pva[e]+2.f*pva[e+1]+pva[e+2];
        gpx[e] += (float)smb*ep; gpy[e] += (float)sma*ep; gpz[e] += (float)dva*sp;
        int bm=(int)((win>>e)&1u), b1=(int)((win>>(e+1))&1u), bp=(int)((win>>(e+2))&1u);
        int et = bp-bm, st = bm+2*b1+bp;
        gtx[e] += smb*et; gty[e] += sma*et; gtz[e] += dva*st;
      }
    }
  }
  float4 X0 = *(const float4*)&P[v0];
  float4 X1 = *(const float4*)&P[VOL+v0];
  ushort4 SK = *(const ushort4*)&skelp[n0];
  uchar4 DT = *(const uchar4*)&acc[n0];
  uchar4 DH = *(const uchar4*)&acc[NTOT+n0];
  int wi0 = n0>>6, bit0 = n0&63;
  int ybq = (int)((ybits[wi0]>>bit0)&0xFull);
  int hdq = (int)((hbits[wi0]>>bit0)&0xFull);
  int sTq = (int)((skel2[wi0]>>bit0)&0xFull);
  int sHq = (int)((skel2[NWORDS+wi0]>>bit0)&0xFull);
  float fsob=0,fcl1=0,fcl2=0,fcl3=0,fcl4=0,fi1=0,fun1=0,fi2=0,fun2=0;
  #pragma unroll
  for(int e=0;e<4;e++){
    float ftx=(float)gtx[e], fty=(float)gty[e], ftz=(float)gtz[e];
    float np_=sqrtf(gpx[e]*gpx[e]+gpy[e]*gpy[e]+gpz[e]*gpz[e]);
    float nt_=sqrtf(ftx*ftx+fty*fty+ftz*ftz);
    float ip=1.f/fmaxf(np_,1e-12f), it=1.f/fmaxf(nt_,1e-12f);
    float num=(gpx[e]*ftx+gpy[e]*fty+gpz[e]*ftz)*ip*it;
    float den=fmaxf((np_*ip)*(nt_*it),1e-8f);
    fsob += num/den;
    int yb=(ybq>>e)&1, hd=(hdq>>e)&1, sT=(sTq>>e)&1, sH=(sHq>>e)&1;
    float dT=(float)((const u8*)&DT)[e], dH=(float)((const u8*)&DH)[e];
    float x0v=((const float*)&X0)[e], x1v=((const float*)&X1)[e];
    float p = 1.f/(1.f+__expf(x0v-x1v));
    float sk = h2f(((const u16*)&SK)[e]);
    fcl1 += sk*(float)yb;
    fcl2 += sk;
    float q_vl = yb ? fminf(dT,rmaxT_[b])/rmaxT_[b] : 0.f;
    if (sT){
      fcl3 += p; fcl4 += 1.f;
      float t=(rmaxT_[b]-dT+rminT_[b])/rmaxT_[b]; float q_sl=t*t;
      float q_vp = fminf(dH,rmaxH_[b])/rmaxH_[b]*p;
      fi2  += q_sl*__powf(q_vp+1e-4f,0.7f)*q_sl;
      fun2 += q_sl*(0.1f*q_vp+0.9f*q_sl);
    }
    if (sH & hd){
      float t=(rmaxH_[b]-dH+rminH_[b])/rmaxH_[b]; float q_sp=t*t*p;
      fi1  += q_sp*__powf(q_sp+1e-4f,0.7f)*q_vl;
      fun1 += q_sp*(0.1f*q_sp+0.9f*q_vl);
    }
  }
  __shared__ double sw[9][4];
  int wid = threadIdx.x>>6, lane = threadIdx.x&63;
  double vals[9] = {fsob,fcl1,fcl2,fcl3,fcl4,fi1,fun1,fi2,fun2};
  #pragma unroll
  for(int s=0;s<9;s++){ double rr = wred(vals[s]); if(lane==0) sw[s][wid]=rr; }
  __syncthreads();
  if(threadIdx.x==0){
    #pragma unroll
    for(int s=0;s<9;s++) part1[(size_t)s*PC1 + blockIdx.x] = sw[s][0]+sw[s][1]+sw[s][2]+sw[s][3];
  }
}

// ---------------- two-stage finalize ----------------
__global__ __launch_bounds__(256) void k_reduce_mid(const double* __restrict__ part0,
                                                    const double* __restrict__ part1,
                                                    double* __restrict__ tot){
  int s = blockIdx.x;
  const double* src; int n;
  if (s < 5){ src = part0 + (size_t)s*PC0; n = PC0; }
  else      { src = part1 + (size_t)(s-5)*PC1; n = PC1; }
  double v=0;
  for(int i=threadIdx.x;i<n;i+=256) v += src[i];
  __shared__ double sd[256];
  sd[threadIdx.x]=v; __syncthreads();
  for(int k=128;k>0;k>>=1){ if((int)threadIdx.x<k) sd[threadIdx.x]+=sd[threadIdx.x+k]; __syncthreads(); }
  if(threadIdx.x==0) tot[s]=sd[0];
}

__global__ void k_fin(const double* __restrict__ tot, float* __restrict__ out){
  if(threadIdx.x==0 && blockIdx.x==0){
    const double N = (double)NTOT;
    double ce = tot[0]/N;
    double tp=tot[1], fp=tot[2]-tot[1], fn=tot[3]-tot[1];
    double dice = -((2.0*tp+1e-5)/(2.0*tp+fp+fn+1e-5));
    double conn = tot[4]/(2.0*N);
    double dir  = 1.0 - tot[5]/N;
    double tprec = (tot[6]+1.0)/(tot[7]+1.0);
    double tsens = (tot[8]+1.0)/(tot[9]+1.0);
    double cld = 1.0 - 2.0*tprec*tsens/(tprec+tsens);
    double u1 = 1.0 - (tot[10]+1.0)/(tot[11]+1.0);
    double u2 = 1.0 - (tot[12]+1.0)/(tot[13]+1.0);
    out[0] = (float)(dice+ce+cld+dir+conn+u1+u2);
  }
}

extern "C" void kernel_launch(void* const* d_in, const int* in_sizes, int n_in,
                              void* d_out, int out_size, void* d_ws, size_t ws_size,
                              hipStream_t stream)
{
  (void)in_sizes; (void)n_in; (void)out_size; (void)ws_size;
  const float* net = (const float*)d_in[0];
  const int*   tgt = (const int*)d_in[1];
  float* out = (float*)d_out;
  char* w = (char*)d_ws;
  const size_t MB = 1024*1024;
  u16* F1 = (u16*)(w + 0*MB);
  u16* F2 = (u16*)(w + 4*MB);              // skel_pred
  u16* F3 = (u16*)(w + 8*MB);
  u64* ybits = (u64*)(w + 12*MB);
  u64* hbits = ybits + NWORDS;
  u64* skel2 = hbits + NWORDS;
  u64* bping = skel2 + 2*NWORDS;
  u64* bpong = bping + 2*NWORDS;
  u8*  dA    = (u8*)(bpong + 2*NWORDS);
  u8*  dB    = dA + (size_t)2*NTOT;
  double* part0 = (double*)(dB + (size_t)2*NTOT);
  double* part1 = part0 + (size_t)5*PC0;
  double* tot   = part1 + (size_t)9*PC1;
  u8* pmaxv = (u8*)(tot + 16);
  u8* pminv = pmaxv + 16384;
  u32* mm  = (u32*)(pminv + 16384);

  k_init<<<PC0, 256, 0, stream>>>(net, tgt, F1, ybits, hbits, bping, part0);

  bskel<true><<<128,256,0,stream>>>(bping, bpong, skel2);
  {
    u64* pi=bping; u64* po=bpong;
    for(int i=0;i<10;i++){ bskel<false><<<128,256,0,stream>>>(pi,po,skel2); u64* t=pi; pi=po; po=t; }
  }

  // float soft_skel(prob, 10) = 11 d-terms: 5 packed double-steps + 1 packed single
  fskel2<true><<<2048,256,0,stream>>>(F1, F3, F2);
  fskel2<false><<<2048,256,0,stream>>>(F3, F1, F2);
  fskel2<false><<<2048,256,0,stream>>>(F1, F3, F2);
  fskel2<false><<<2048,256,0,stream>>>(F3, F1, F2);
  fskel2<false><<<2048,256,0,stream>>>(F1, F3, F2);
  fskel1<<<2048,256,0,stream>>>(F3, F2);

  const int GE = (2*NTOT)/256;
  edt_px<<<GE,256,0,stream>>>(ybits, hbits, dA);
  edt_py<<<GE,256,0,stream>>>(dA, dB);
  edt_pz_part<<<GE,256,0,stream>>>(dB, dA, skel2, hbits, pmaxv, pminv);
  rmm2<<<1,256,0,stream>>>(pmaxv, pminv, mm);

  k_tail<<<PC1,256,0,stream>>>(net, F2, ybits, hbits, skel2, dA, mm, part1);
  k_reduce_mid<<<14,256,0,stream>>>(part0, part1, tot);
  k_fin<<<1,64,0,stream>>>(tot, out);
}

// Round 11
// 321.548 us; speedup vs baseline: 1.7480x; 1.0641x over previous
//
#include <hip/hip_runtime.h>
#include <math.h>

typedef unsigned long long u64;
typedef unsigned int u32;
typedef unsigned short u16;
typedef unsigned char u8;

#define VOL 1048576              // 64*128*128
#define NTOT 2097152             // 2 batches
#define NWORDS 32768             // NTOT/64
#define PC0 2048
#define PC1 2048

union HU { u16 u; _Float16 h; };
__device__ __forceinline__ float h2f(u16 u){ HU x; x.u=u; return (float)x.h; }
__device__ __forceinline__ u16 f2h(float f){ HU x; x.h=(_Float16)f; return x.u; }
#define H_ONE2 0x3C003C00u   // pair of 1.0 (erode-neutral)

// packed fp16 min/max (2 voxels per op)
__device__ __forceinline__ u32 pmin(u32 a, u32 b){ u32 r; asm("v_pk_min_f16 %0, %1, %2" : "=v"(r) : "v"(a), "v"(b)); return r; }
__device__ __forceinline__ u32 pmax(u32 a, u32 b){ u32 r; asm("v_pk_max_f16 %0, %1, %2" : "=v"(r) : "v"(a), "v"(b)); return r; }

__device__ __forceinline__ double wred(double v){
  #pragma unroll
  for(int o=32;o;o>>=1) v += __shfl_down(v, o);
  return v;
}

__device__ __forceinline__ u32 nib_compact(u64 v){
  v &= 0x0F0F0F0F0F0F0F0Full;
  v |= v>>4;  v &= 0x00FF00FF00FF00FFull;
  v |= v>>8;  v &= 0x0000FFFF0000FFFFull;
  v |= v>>16;
  return (u32)v;
}

// ---------------- init: prob(fp16 x2 copies), bitmasks, dice/ce/conn sums ----------------
// 4 voxels per thread, 2048 blocks.
__global__ __launch_bounds__(256) void k_init(const float* __restrict__ net, const int* __restrict__ tgt,
    u16* __restrict__ img, u16* __restrict__ prob, u64* __restrict__ ybits, u64* __restrict__ hbits,
    u64* __restrict__ bimg2, double* __restrict__ part)
{
  __shared__ u64 nyb[32], nhb[32];
  __shared__ double sw[5][4];
  int tid = threadIdx.x;
  int r = blockIdx.x*256 + tid;
  int n0 = r<<2;
  int b = n0>>20, v0 = n0&(VOL-1);
  const float* nb = net + (size_t)b*(2*VOL);
  float4 a0 = *(const float4*)&nb[v0];
  float4 a1 = *(const float4*)&nb[VOL+v0];
  int4  tv = *(const int4*)&tgt[n0];
  float x0a[4] = {a0.x,a0.y,a0.z,a0.w};
  float x1a[4] = {a1.x,a1.y,a1.z,a1.w};
  int   ta[4]  = {tv.x,tv.y,tv.z,tv.w};
  double ce=0,tp=0,spr=0,sy=0,conn=0;
  u32 pk[2] = {0,0};
  u32 y4=0, h4=0;
  #pragma unroll
  for(int e=0;e<4;e++){
    float d = x1a[e]-x0a[e];
    int yb = (ta[e]>0) ? 1 : 0;
    float p = 1.f/(1.f+__expf(-d));
    y4 |= (u32)yb<<e;
    h4 |= (u32)(d>0.f)<<e;
    pk[e>>1] |= (u32)f2h(p) << ((e&1)*16);
    ce += (double)(log1pf(__expf(-fabsf(d))) + fmaxf(yb? -d : d, 0.f));
    tp += (double)p*yb;
    spr += (double)p;
    sy += (double)yb;
    conn += (double)((int)((x0a[e]>0.5f)!=(yb!=0)) + (int)((x1a[e]>0.5f)!=(yb!=0)));
  }
  u32* f1 = (u32*)img;
  u32* f4 = (u32*)prob;
  int pi = r<<1;
  f1[pi] = pk[0]; f1[pi+1] = pk[1];
  f4[pi] = pk[0]; f4[pi+1] = pk[1];
  ((u8*)nyb)[tid] = (u8)y4;
  ((u8*)nhb)[tid] = (u8)h4;
  __syncthreads();
  if (tid < 16){
    u64 wy = (u64)nib_compact(nyb[tid*2]) | ((u64)nib_compact(nyb[tid*2+1])<<32);
    u64 wh = (u64)nib_compact(nhb[tid*2]) | ((u64)nib_compact(nhb[tid*2+1])<<32);
    int wi = blockIdx.x*16 + tid;
    ybits[wi]=wy; bimg2[wi]=wy;
    hbits[wi]=wh; bimg2[NWORDS+wi]=wh;
  }
  int wid = tid>>6, lane = tid&63;
  double vals[5] = {ce,tp,spr,sy,conn};
  #pragma unroll
  for(int s=0;s<5;s++){ double rr = wred(vals[s]); if(lane==0) sw[s][wid]=rr; }
  __syncthreads();
  if(tid==0){
    #pragma unroll
    for(int s=0;s<5;s++) part[(size_t)s*PC0 + blockIdx.x] = sw[s][0]+sw[s][1]+sw[s][2]+sw[s][3];
  }
}

// ---------------- fskel2p: TWO soft-skel iterations, x-pair packed fp16 (unchanged r10) ----
template<bool INIT>
__global__ __launch_bounds__(256) void fskel2(const u16* __restrict__ imgin, u16* __restrict__ imgout,
                                              u16* __restrict__ skel)
{
  __shared__ u32 A_[2800];
  __shared__ u32 B_[1728];
  __shared__ u32 C_[1080];
  int bid = blockIdx.x;
  int xb = bid&3, yb=(bid>>2)&15, zb=(bid>>6)&15, b=bid>>10;
  int X0=xb*32, Y0=yb*8, Z0=zb*4;
  const u32* vin = (const u32*)(imgin + (size_t)b*VOL);
  u32* vout = (u32*)(imgout + (size_t)b*VOL);
  u32* skl = (u32*)(skel + (size_t)b*VOL);
  int tid = threadIdx.x;

  {
    int y0 = tid/20, x0 = tid - y0*20;
    int gy0 = Y0-3+y0, gx0 = X0-4+2*x0;
    bool ok0 = ((unsigned)gy0<128u) & ((unsigned)gx0<128u);
    int gb0 = (gy0<<6)+(gx0>>1);
    int t1 = tid+256; int y1 = t1/20, x1 = t1-y1*20;
    int gy1 = Y0-3+y1, gx1 = X0-4+2*x1;
    bool hv1 = tid<24;
    bool ok1 = ((unsigned)gy1<128u) & ((unsigned)gx1<128u);
    int gb1 = (gy1<<6)+(gx1>>1);
    #pragma unroll
    for(int z=0; z<10; ++z){
      int gz = Z0-3+z;
      bool zok = (unsigned)gz<64u;
      int zb2 = gz<<13;
      A_[z*280+tid] = (zok&ok0) ? vin[zb2+gb0] : H_ONE2;
      if (hv1) A_[z*280+t1] = (zok&ok1) ? vin[zb2+gb1] : H_ONE2;
    }
  }
  __syncthreads();
  if (tid < 216){
    int y = tid/18, px = tid - y*18;
    int gy = Y0-2+y;
    bool yok = (unsigned)gy<128u;
    bool xout = ((X0==0)&&(px==0)) || ((X0==96)&&(px==17));
    #pragma unroll
    for(int z=0; z<8; ++z){
      bool zok = (unsigned)(Z0-2+z)<64u;
      u32 v = H_ONE2;
      if (zok && yok && !xout){
        int c = (z+1)*280 + (y+1)*20 + (px+1);
        u32 C0=A_[c], L=A_[c-1], R=A_[c+1];
        u32 SL=(L>>16)|(C0<<16), SR=(C0>>16)|(R<<16);
        u32 m = pmin(pmin(SL,SR), C0);
        m = pmin(m, pmin(A_[c-20],A_[c+20]));
        v = pmin(m, pmin(A_[c-280],A_[c+280]));
      }
      B_[z*216+tid] = v;
    }
  }
  __syncthreads();
  if (tid < 180){
    int y = tid/18, px = tid - y*18;
    int gy = Y0-1+y;
    bool yok = (unsigned)gy<128u;
    bool xout = ((X0==0)&&(px==0)) || ((X0==96)&&(px==17));
    bool ctr = (px>=1)&&(px<=16)&&(y>=1)&&(y<=8);
    int pxm = (px>0)? px-1 : 0;
    int pxp = (px<17)? px+1 : 17;
    int gb = (gy<<6)+((X0-2+2*px)>>1);
    #pragma unroll
    for(int z=0; z<6; ++z){
      int gz = Z0-1+z;
      bool zok = (unsigned)gz<64u;
      u32 v = 0;
      if (zok && yok && !xout){
        int c = (z+1)*216 + (y+1)*18;
        u32 C0=B_[c+px], L=B_[c+pxm], R=B_[c+pxp];
        u32 SL=(L>>16)|(C0<<16), SR=(C0>>16)|(R<<16);
        u32 m = pmin(pmin(SL,SR), C0);
        m = pmin(m, pmin(B_[c+px-18],B_[c+px+18]));
        v = pmin(m, pmin(B_[c-216+px],B_[c+216+px]));
      }
      C_[z*180+tid] = v;
      if (ctr && z>=1 && z<=4)
        vout[(gz<<13)+gb] = v;
    }
  }
  int col = tid>>1, zh = tid&1;
  int oy = col>>4, opx = col&15;
  u32 ek0[2], ek1[2];
  #pragma unroll
  for(int j=0;j<2;j++){
    int z = zh*2+j;
    ek0[j] = A_[(z+3)*280+(oy+3)*20+(opx+2)];
    ek1[j] = B_[(z+2)*216+(oy+2)*18+(opx+1)];
  }
  __syncthreads();
  u32* X1 = A_; u32* X2 = A_ + 960;
  if (tid < 160){
    int y = tid>>4, px = tid&15;
    int px1 = px+1;
    int gy = Y0-1+y;
    bool yok = (unsigned)gy<128u;
    bool mlo = (X0==0)&&(px==0);
    bool mhi = (X0==96)&&(px==15);
    #pragma unroll
    for(int z=0; z<6; ++z){
      bool zok = (unsigned)(Z0-1+z)<64u;
      {
        int c = (z+1)*216 + (y+1)*18 + px1;
        u32 C0=B_[c], L=B_[c-1], R=B_[c+1];
        if (mlo) L = 0;
        if (mhi) R = 0;
        u32 SL=(L>>16)|(C0<<16), SR=(C0>>16)|(R<<16);
        u32 v = pmax(pmax(SL,SR), C0);
        X1[z*160+tid] = (zok&&yok) ? v : 0;
      }
      {
        int c = z*180 + y*18 + px1;
        u32 C0=C_[c], L=C_[c-1], R=C_[c+1];
        u32 SL=(L>>16)|(C0<<16), SR=(C0>>16)|(R<<16);
        X2[z*160+tid] = pmax(pmax(SL,SR), C0);
      }
    }
  }
  __syncthreads();
  u32* Y1 = B_; u32* Y2 = B_ + 768;
  {
    int arr = tid>>7, rem = tid&127;
    int y = rem>>4, px = rem&15;
    const u32* Xs = arr ? X2 : X1;
    u32* Ys = arr ? Y2 : Y1;
    #pragma unroll
    for(int z=0; z<6; ++z){
      int c = z*160 + y*16 + px;
      Ys[z*128 + rem] = pmax(pmax(Xs[c], Xs[c+16]), Xs[c+32]);
    }
  }
  __syncthreads();
  {
    int gx = X0 + 2*opx;
    #pragma unroll
    for(int j=0;j<2;j++){
      int z = zh*2+j;
      int gz = Z0+z;
      int c = z*128 + oy*16 + opx;
      u32 o1 = pmax(pmax(Y1[c], Y1[c+128]), Y1[c+256]);
      u32 o2 = pmax(pmax(Y2[c], Y2[c+128]), Y2[c+256]);
      u32 idx = (u32)((gz<<13) + ((Y0+oy)<<6) + (gx>>1));
      float d0l = fmaxf(h2f((u16)ek0[j]) - h2f((u16)o1), 0.f);
      float d0h = fmaxf(h2f((u16)(ek0[j]>>16)) - h2f((u16)(o1>>16)), 0.f);
      float d1l = fmaxf(h2f((u16)ek1[j]) - h2f((u16)o2), 0.f);
      float d1h = fmaxf(h2f((u16)(ek1[j]>>16)) - h2f((u16)(o2>>16)), 0.f);
      float sl_, sh_;
      if (INIT){ sl_ = d0l; sh_ = d0h; }
      else {
        u32 swv = skl[idx];
        sl_ = h2f((u16)swv); sh_ = h2f((u16)(swv>>16));
        sl_ += fmaxf(d0l - sl_*d0l, 0.f); sh_ += fmaxf(d0h - sh_*d0h, 0.f);
      }
      sl_ += fmaxf(d1l - sl_*d1l, 0.f); sh_ += fmaxf(d1h - sh_*d1h, 0.f);
      skl[idx] = (u32)f2h(sl_) | ((u32)f2h(sh_)<<16);
    }
  }
}

// ---------------- fskel1p: single iteration (last d-term), packed (unchanged r10) ----------------
__global__ __launch_bounds__(256) void fskel1(const u16* __restrict__ imgin, u16* __restrict__ skel)
{
  __shared__ u32 A2[1920];
  __shared__ u32 B2[1080];
  int bid = blockIdx.x;
  int xb = bid&3, yb=(bid>>2)&15, zb=(bid>>6)&15, b=bid>>10;
  int X0=xb*32, Y0=yb*8, Z0=zb*4;
  const u32* vin = (const u32*)(imgin + (size_t)b*VOL);
  u32* skl = (u32*)(skel + (size_t)b*VOL);
  int tid = threadIdx.x;
  if (tid < 240){
    int y0 = tid/20, x0 = tid - y0*20;
    int gy0 = Y0-2+y0, gx0 = X0-4+2*x0;
    bool ok0 = ((unsigned)gy0<128u) & ((unsigned)gx0<128u);
    int gb0 = (gy0<<6)+(gx0>>1);
    #pragma unroll
    for(int z=0; z<8; ++z){
      int gz = Z0-2+z;
      bool zok = (unsigned)gz<64u;
      A2[z*240+tid] = (zok&ok0) ? vin[(gz<<13)+gb0] : H_ONE2;
    }
  }
  __syncthreads();
  if (tid < 180){
    int y = tid/18, px = tid - y*18;
    int gy = Y0-1+y;
    bool yok = (unsigned)gy<128u;
    bool xout = ((X0==0)&&(px==0)) || ((X0==96)&&(px==17));
    int pxm = (px>0)? px-1 : 0;
    int pxp = (px<17)? px+1 : 17;
    #pragma unroll
    for(int z=0; z<6; ++z){
      bool zok = (unsigned)(Z0-1+z)<64u;
      u32 v = 0;
      if (zok && yok && !xout){
        int c = (z+1)*240 + (y+1)*20;
        u32 C0=A2[c+px+1], L=A2[c+pxm+1], R=A2[c+pxp+1];
        u32 SL=(L>>16)|(C0<<16), SR=(C0>>16)|(R<<16);
        u32 m = pmin(pmin(SL,SR), C0);
        m = pmin(m, pmin(A2[c+px+1-20],A2[c+px+1+20]));
        v = pmin(m, pmin(A2[c-240+px+1],A2[c+240+px+1]));
      }
      B2[z*180+tid] = v;
    }
  }
  int col = tid>>1, zh = tid&1;
  int oy = col>>4, opx = col&15;
  u32 ek[2];
  #pragma unroll
  for(int j=0;j<2;j++){
    int z = zh*2+j;
    ek[j] = A2[(z+2)*240+(oy+2)*20+(opx+2)];
  }
  __syncthreads();
  u32* X = A2;
  if (tid < 160){
    int y = tid>>4, px = tid&15;
    int px1 = px+1;
    #pragma unroll
    for(int z=0; z<6; ++z){
      int c = z*180 + y*18 + px1;
      u32 C0=B2[c], L=B2[c-1], R=B2[c+1];
      u32 SL=(L>>16)|(C0<<16), SR=(C0>>16)|(R<<16);
      X[z*160+tid] = pmax(pmax(SL,SR), C0);
    }
  }
  __syncthreads();
  u32* Y = B2;
  if (tid < 128){
    int y = tid>>4, px = tid&15;
    #pragma unroll
    for(int z=0; z<6; ++z){
      int c = z*160 + y*16 + px;
      Y[z*128 + tid] = pmax(pmax(X[c], X[c+16]), X[c+32]);
    }
  }
  __syncthreads();
  {
    int gx = X0 + 2*opx;
    #pragma unroll
    for(int j=0;j<2;j++){
      int z = zh*2+j;
      int gz = Z0+z;
      int c = z*128 + oy*16 + opx;
      u32 o = pmax(pmax(Y[c], Y[c+128]), Y[c+256]);
      u32 idx = (u32)((gz<<13) + ((Y0+oy)<<6) + (gx>>1));
      float dl = fmaxf(h2f((u16)ek[j]) - h2f((u16)o), 0.f);
      float dh = fmaxf(h2f((u16)(ek[j]>>16)) - h2f((u16)(o>>16)), 0.f);
      u32 swv = skl[idx];
      float sl_ = h2f((u16)swv), sh_ = h2f((u16)(swv>>16));
      sl_ += fmaxf(dl - sl_*dl, 0.f); sh_ += fmaxf(dh - sh_*dh, 0.f);
      skl[idx] = (u32)f2h(sl_) | ((u32)f2h(sh_)<<16);
    }
  }
}

// ---------------- systolic binary soft-skel iteration (unchanged r10) ----------------
__device__ __forceinline__ u64 berode_x(const u64* P, int tid){
  u64 c = P[tid];
  if (tid & 1) return c & ((c<<1)|(P[tid-1]>>63)) & ((c>>1)|(1ull<<63));
  else         return c & ((c<<1)|1ull) & ((c>>1)|(P[tid+1]<<63));
}
__device__ __forceinline__ u64 bdilate_x(const u64* P, int tid){
  u64 c = P[tid];
  if (tid & 1) return c | (c<<1) | (P[tid-1]>>63) | (c>>1);
  else         return c | (c<<1) | (c>>1) | (P[tid+1]<<63);
}

template<bool INIT>
__global__ __launch_bounds__(256) void bskel(const u64* __restrict__ imgin, u64* __restrict__ imgout,
                                             u64* __restrict__ skel)
{
  __shared__ u64 simg[4][256];
  __shared__ u64 se1[6][256];
  __shared__ u64 se2[2][256];
  __shared__ u64 sM[4][256];
  int bid = blockIdx.x;
  int tzb = bid & 31, b = (bid>>5)&1, m = bid>>6;
  int z0 = tzb*2, z1 = z0+2;
  size_t base = (size_t)m*NWORDS + (size_t)b*16384;
  const u64* vin = imgin + base;
  u64* vout = imgout + base;
  u64* skl = skel + base;
  int tid = threadIdx.x;
  int y = tid>>1;

  for (int s = z0-3; s <= z1+6; ++s){
    if (s <= z1+2)
      simg[(s+96)&3][tid] = ((unsigned)s<64u) ? vin[(s<<8)+tid] : ~0ull;
    { int t = s-2;
      if (t >= z0-2 && t <= z1+1){
        u64 r = ~0ull;
        if ((unsigned)t<64u){
          const u64* P = simg[(t+96)&3];
          if (INIT) r = P[tid];
          else {
            r = berode_x(P, tid);
            if(y>0)   r &= P[tid-2];
            if(y<127) r &= P[tid+2];
            r &= simg[(t-1+96)&3][tid] & simg[(t+1+96)&3][tid];
          }
        }
        se1[(t+96)%6][tid] = r;
      }
    }
    { int t = s-4;
      if (t >= z0-1 && t <= z1){
        u64 r = 0;
        if ((unsigned)t<64u){
          const u64* P = se1[(t+96)%6];
          r = berode_x(P, tid);
          if(y>0)   r &= P[tid-2];
          if(y<127) r &= P[tid+2];
          r &= se1[(t-1+96)%6][tid] & se1[(t+1+96)%6][tid];
        }
        se2[(t+96)&1][tid] = r;
      }
    }
    { int t = s-5;
      if (t >= z0-1 && t <= z1){
        const u64* P = se2[(t+96)&1];
        u64 dm = bdilate_x(P, tid);
        if(y>0)   dm |= bdilate_x(P, tid-2);
        if(y<127) dm |= bdilate_x(P, tid+2);
        sM[(t+96)&3][tid] = dm;
      }
    }
    { int z = s-7;
      if (z >= z0 && z < z1){
        u64 open_ = sM[(z-1+96)&3][tid] | sM[(z+96)&3][tid] | sM[(z+1+96)&3][tid];
        u64 e1v = se1[(z+96)%6][tid];
        u64 d = e1v & ~open_;
        int gw = (z<<8)+tid;
        if (INIT) skl[gw] = d;
        else { skl[gw] |= d; vout[gw] = e1v; }
      }
    }
    __syncthreads();
  }
}

// ---------------- separable Chebyshev EDT (unchanged r10) ----------------
__global__ __launch_bounds__(256) void edt_px(const u64* __restrict__ yb, const u64* __restrict__ hb,
                                              u8* __restrict__ d)
{
  int g = blockIdx.x*256 + threadIdx.x;
  int m = g >> 21;
  int n = g & (NTOT-1);
  const u64* bits = m ? hb : yb;
  int x = n & 127;
  int row = n >> 7;
  u64 w0 = bits[row*2], w1 = bits[row*2+1];
  int a = x - 31;
  u64 win;
  if (a < 0)        win = w0 << (-a);
  else if (a == 0)  win = w0;
  else if (a < 64)  win = (w0 >> a) | (w1 << (64-a));
  else              win = w1 >> (a-64);
  if (x < 31)  win |= (1ull << (31-x)) - 1;
  if (x > 95)  win |= (~0ull) << (159-x);
  u64 inv = ~win;
  u64 tl = inv & 0xFFFFFFFFull;
  u64 tr = inv >> 31;
  int dl = tl ? (31 - (63 - __clzll(tl))) : 99;
  int dr = tr ? (__ffsll((unsigned long long)tr) - 1) : 99;
  d[(size_t)g] = (u8)min(min(dl, dr), 16);
}

__global__ __launch_bounds__(256) void edt_py(const u8* __restrict__ din, u8* __restrict__ dout){
  int g = blockIdx.x*256 + threadIdx.x;
  int n = g & (NTOT-1);
  int c = (n >> 7) & 127;
  size_t idx = (size_t)g;
  int best = din[idx];
  #pragma unroll 4
  for (int k=1; k<=16; ++k){
    if (best <= k) break;
    int v = 255;
    if (c-k >= 0)   v = din[idx - (size_t)k*128];
    if (c+k < 128)  v = min(v, (int)din[idx + (size_t)k*128]);
    best = min(best, max(k, v));
  }
  dout[idx] = (u8)best;
}

__global__ __launch_bounds__(256) void edt_pz_part(const u8* __restrict__ din, u8* __restrict__ dout,
    const u64* __restrict__ skel2, const u64* __restrict__ hbits,
    u8* __restrict__ pmaxv, u8* __restrict__ pminv)
{
  int tid = threadIdx.x;
  int g = blockIdx.x*256 + tid;
  int m = g >> 21;
  int n = g & (NTOT-1);
  int c = (n >> 14) & 63;
  size_t idx = (size_t)g;
  int best = din[idx];
  #pragma unroll 4
  for (int k=1; k<=16; ++k){
    if (best <= k) break;
    int v = 255;
    if (c-k >= 0)  v = din[idx - (size_t)k*16384];
    if (c+k < 64)  v = min(v, (int)din[idx + (size_t)k*16384]);
    best = min(best, max(k, v));
  }
  dout[idx] = (u8)best;
  int wi = n>>6, bit = n&63;
  u64 sbit = m ? (skel2[NWORDS+wi] & hbits[wi]) : skel2[wi];
  u32 r = (u32)((sbit>>bit)&1ull) ? (u32)best : 0u;
  __shared__ u32 sx[256], sn_[256];
  sx[tid]=r; sn_[tid]=r;
  __syncthreads();
  for(int s=128;s>0;s>>=1){
    if(tid<s){
      if(sx[tid+s]>sx[tid]) sx[tid]=sx[tid+s];
      if(sn_[tid+s]<sn_[tid]) sn_[tid]=sn_[tid+s];
    }
    __syncthreads();
  }
  if(tid==0){ pmaxv[blockIdx.x]=(u8)sx[0]; pminv[blockIdx.x]=(u8)sn_[0]; }
}

__global__ __launch_bounds__(256) void rmm2(const u8* __restrict__ pmaxv, const u8* __restrict__ pminv,
                                            u32* __restrict__ mm){
  __shared__ u8 smx[4][256], smn[4][256];
  int tid = threadIdx.x;
  u8 mx[4]={0,0,0,0}, mn[4]={255,255,255,255};
  for(int i=tid;i<16384;i+=256){
    int sel=i>>13, b=(i>>12)&1, cc=sel*2+b;
    u8 a=pmaxv[i], d=pminv[i];
    if(a>mx[cc]) mx[cc]=a;
    if(d<mn[cc]) mn[cc]=d;
  }
  #pragma unroll
  for(int cc=0;cc<4;cc++){ smx[cc][tid]=mx[cc]; smn[cc][tid]=mn[cc]; }
  __syncthreads();
  for(int s=128;s>0;s>>=1){
    if(tid<s){
      #pragma unroll
      for(int cc=0;cc<4;cc++){
        if(smx[cc][tid+s]>smx[cc][tid]) smx[cc][tid]=smx[cc][tid+s];
        if(smn[cc][tid+s]<smn[cc][tid]) smn[cc][tid]=smn[cc][tid+s];
      }
    }
    __syncthreads();
  }
  if(tid==0){
    #pragma unroll
    for(int cc=0;cc<4;cc++){
      int sel=cc>>1, b=cc&1;
      mm[sel*4+b]   = (u32)smx[cc][0];
      mm[sel*4+2+b] = (u32)smn[cc][0];
    }
  }
}

// ---------------- k_tail: LDS-tiled separable sobel + final reduce ----------------
// tile 32x8x4, 2048 blocks. wx=1_z*sm_y*dv_x, wy=sm_z*1_y*dv_x, wz=dv_z*1_y*sm_x.
__global__ __launch_bounds__(256) void k_tail(const float* __restrict__ net, const u16* __restrict__ prob,
    const u16* __restrict__ skelp, const u64* __restrict__ ybits, const u64* __restrict__ hbits,
    const u64* __restrict__ skel2, const u8* __restrict__ acc, const u32* __restrict__ mm,
    double* __restrict__ part1)
{
  __shared__ float lp[2040];     // [6][10][34] logits ch0, zero-padded
  __shared__ float dxp[1920];    // [6][10][32] x-deriv
  __shared__ float sxp[1920];    // [6][10][32] x-smooth
  __shared__ char  dxt8[1920];
  __shared__ u8    sxt8[1920];
  __shared__ u64   wrow[60];     // [6][10] target bit windows (bit i <-> gx=X0-1+i)
  __shared__ double sw[9][4];
  int tid = threadIdx.x;
  int bid = blockIdx.x;
  int xb = bid&3, ybk=(bid>>2)&15, zbk=(bid>>6)&15, b=bid>>10;
  int X0=xb*32, Y0=ybk*8, Z0=zbk*4;
  const float* P = net + (size_t)b*(2*VOL);
  float rmaxT = fmaxf((float)mm[b],1.f),   rminT = fmaxf((float)mm[2+b],1.f);
  float rmaxH = fmaxf((float)mm[4+b],1.f), rminH = fmaxf((float)mm[6+b],1.f);
  // P0: load logits + bit windows
  for (int idx=tid; idx<2040; idx+=256){
    int zr = idx/340; int rem = idx-zr*340; int yr = rem/34; int xi = rem-yr*34;
    int gz=Z0-1+zr, gy=Y0-1+yr, gx=X0-1+xi;
    float v = 0.f;
    if((unsigned)gz<64u && (unsigned)gy<128u && (unsigned)gx<128u)
      v = P[(gz<<14)+(gy<<7)+gx];
    lp[idx] = v;
  }
  if (tid < 60){
    int zr = tid/10, yr = tid-zr*10;
    int gz=Z0-1+zr, gy=Y0-1+yr;
    u64 wn = 0;
    if((unsigned)gz<64u && (unsigned)gy<128u){
      const u64* yw = ybits + ((size_t)b<<14) + (gz<<8) + (gy<<1);
      u64 w0 = yw[0], w1 = yw[1];
      if (X0==0) wn = w0<<1;
      else { int s = X0-1; wn = (s<64) ? ((w0>>s)|(w1<<(64-s))) : (w1>>(s-64)); }
    }
    wrow[tid] = wn;
  }
  __syncthreads();
  // P1: x-pass
  for (int idx=tid; idx<1920; idx+=256){
    int zr = idx/320; int rem = idx-zr*320; int yr = rem>>5; int x = rem&31;
    int c = zr*340 + yr*34 + x;
    float l0=lp[c], l1=lp[c+1], l2=lp[c+2];
    dxp[idx] = l2-l0;
    sxp[idx] = l0+2.f*l1+l2;
    u64 wn = wrow[zr*10+yr];
    int bm=(int)((wn>>x)&1ull), b1=(int)((wn>>(x+1))&1ull), bp=(int)((wn>>(x+2))&1ull);
    dxt8[idx] = (char)(bp-bm);
    sxt8[idx] = (u8)(bm+2*b1+bp);
  }
  __syncthreads();
  // P2: y-combine into registers, then z-combine + loss
  int oy = tid>>5, ox = tid&31;
  float A1[6],A2[6],A3[6];
  int   B1v[6],B2v[6],B3v[6];
  #pragma unroll
  for(int zr=0; zr<6; ++zr){
    int base = zr*320 + oy*32 + ox;
    float d0=dxp[base], d1=dxp[base+32], d2=dxp[base+64];
    A1[zr] = d0+2.f*d1+d2;
    A2[zr] = d0+d1+d2;
    float s0=sxp[base], s1=sxp[base+32], s2=sxp[base+64];
    A3[zr] = s0+s1+s2;
    int t0=dxt8[base], t1=dxt8[base+32], t2=dxt8[base+64];
    B1v[zr] = t0+2*t1+t2;
    B2v[zr] = t0+t1+t2;
    int u0=sxt8[base], u1=sxt8[base+32], u2=sxt8[base+64];
    B3v[zr] = u0+u1+u2;
  }
  double fsob=0,cl1=0,cl2=0,cl3=0,cl4=0,i1=0,un1=0,i2=0,un2=0;
  #pragma unroll
  for(int zc=0; zc<4; ++zc){
    float gpx = A1[zc]+A1[zc+1]+A1[zc+2];
    float gpy = A2[zc]+2.f*A2[zc+1]+A2[zc+2];
    float gpz = A3[zc+2]-A3[zc];
    float ftx = (float)(B1v[zc]+B1v[zc+1]+B1v[zc+2]);
    float fty = (float)(B2v[zc]+2*B2v[zc+1]+B2v[zc+2]);
    float ftz = (float)(B3v[zc+2]-B3v[zc]);
    float s1 = gpx*gpx+gpy*gpy+gpz*gpz;
    float s2 = ftx*ftx+fty*fty+ftz*ftz;
    if (s1>0.f && s2>0.f){
      float ip = rsqrtf(s1), it = rsqrtf(s2);
      fsob += (double)((gpx*ftx+gpy*fty+gpz*ftz)*ip*it);
    }
    // per-voxel loss terms
    int gz=Z0+zc, gy=Y0+oy, gx=X0+ox;
    int n = (b<<20)+(gz<<14)+(gy<<7)+gx;
    int yb = (int)((wrow[(zc+1)*10+(oy+1)] >> (ox+1)) & 1ull);
    int wi = n>>6, bit = n&63;
    int hd = (int)((hbits[wi]>>bit)&1ull);
    int sT = (int)((skel2[wi]>>bit)&1ull);
    int sH = (int)((skel2[NWORDS+wi]>>bit)&1ull);
    float dT = (float)acc[n];
    float dH = (float)acc[(size_t)NTOT+n];
    float p  = h2f(prob[n]);
    float sk = h2f(skelp[n]);
    cl1 += (double)(sk*(float)yb);
    cl2 += (double)sk;
    float q_vl = yb ? fminf(dT,rmaxT)/rmaxT : 0.f;
    if (sT){
      cl3 += (double)p; cl4 += 1.0;
      float t=(rmaxT-dT+rminT)/rmaxT; float q_sl=t*t;
      float q_vp = fminf(dH,rmaxH)/rmaxH*p;
      i2  += (double)(q_sl*__powf(q_vp+1e-4f,0.7f)*q_sl);
      un2 += (double)(q_sl*(0.1f*q_vp+0.9f*q_sl));
    }
    if (sH & hd){
      float t=(rmaxH-dH+rminH)/rmaxH; float q_sp=t*t*p;
      i1  += (double)(q_sp*__powf(q_sp+1e-4f,0.7f)*q_vl);
      un1 += (double)(q_sp*(0.1f*q_sp+0.9f*q_vl));
    }
  }
  int wid = tid>>6, lane = tid&63;
  double vals[9] = {fsob,cl1,cl2,cl3,cl4,i1,un1,i2,un2};
  #pragma unroll
  for(int s=0;s<9;s++){ double rr = wred(vals[s]); if(lane==0) sw[s][wid]=rr; }
  __syncthreads();
  if(tid==0){
    #pragma unroll
    for(int s=0;s<9;s++) part1[(size_t)s*PC1 + bid] = sw[s][0]+sw[s][1]+sw[s][2]+sw[s][3];
  }
}

// ---------------- two-stage finalize ----------------
__global__ __launch_bounds__(256) void k_reduce_mid(const double* __restrict__ part0,
                                                    const double* __restrict__ part1,
                                                    double* __restrict__ tot){
  int s = blockIdx.x;
  const double* src; int n;
  if (s < 5){ src = part0 + (size_t)s*PC0; n = PC0; }
  else      { src = part1 + (size_t)(s-5)*PC1; n = PC1; }
  double v=0;
  for(int i=threadIdx.x;i<n;i+=256) v += src[i];
  __shared__ double sd[256];
  sd[threadIdx.x]=v; __syncthreads();
  for(int k=128;k>0;k>>=1){ if((int)threadIdx.x<k) sd[threadIdx.x]+=sd[threadIdx.x+k]; __syncthreads(); }
  if(threadIdx.x==0) tot[s]=sd[0];
}

__global__ void k_fin(const double* __restrict__ tot, float* __restrict__ out){
  if(threadIdx.x==0 && blockIdx.x==0){
    const double N = (double)NTOT;
    double ce = tot[0]/N;
    double tp=tot[1], fp=tot[2]-tot[1], fn=tot[3]-tot[1];
    double dice = -((2.0*tp+1e-5)/(2.0*tp+fp+fn+1e-5));
    double conn = tot[4]/(2.0*N);
    double dir  = 1.0 - tot[5]/N;
    double tprec = (tot[6]+1.0)/(tot[7]+1.0);
    double tsens = (tot[8]+1.0)/(tot[9]+1.0);
    double cld = 1.0 - 2.0*tprec*tsens/(tprec+tsens);
    double u1 = 1.0 - (tot[10]+1.0)/(tot[11]+1.0);
    double u2 = 1.0 - (tot[12]+1.0)/(tot[13]+1.0);
    out[0] = (float)(dice+ce+cld+dir+conn+u1+u2);
  }
}

extern "C" void kernel_launch(void* const* d_in, const int* in_sizes, int n_in,
                              void* d_out, int out_size, void* d_ws, size_t ws_size,
                              hipStream_t stream)
{
  (void)in_sizes; (void)n_in; (void)out_size; (void)ws_size;
  const float* net = (const float*)d_in[0];
  const int*   tgt = (const int*)d_in[1];
  float* out = (float*)d_out;
  char* w = (char*)d_ws;
  const size_t MB = 1024*1024;
  u16* F1 = (u16*)(w + 0*MB);              // prob img ping (fp16)
  u16* F2 = (u16*)(w + 4*MB);              // skel_pred
  u16* F3 = (u16*)(w + 8*MB);              // img pong
  u16* F4 = (u16*)(w + 12*MB);             // pristine prob copy
  u64* ybits = (u64*)(w + 16*MB);
  u64* hbits = ybits + NWORDS;
  u64* skel2 = hbits + NWORDS;
  u64* bping = skel2 + 2*NWORDS;
  u64* bpong = bping + 2*NWORDS;
  u8*  dA    = (u8*)(bpong + 2*NWORDS);
  u8*  dB    = dA + (size_t)2*NTOT;
  double* part0 = (double*)(dB + (size_t)2*NTOT);
  double* part1 = part0 + (size_t)5*PC0;
  double* tot   = part1 + (size_t)9*PC1;
  u8* pmaxv = (u8*)(tot + 16);
  u8* pminv = pmaxv + 16384;
  u32* mm  = (u32*)(pminv + 16384);

  k_init<<<PC0, 256, 0, stream>>>(net, tgt, F1, F4, ybits, hbits, bping, part0);

  bskel<true><<<128,256,0,stream>>>(bping, bpong, skel2);
  {
    u64* pi=bping; u64* po=bpong;
    for(int i=0;i<10;i++){ bskel<false><<<128,256,0,stream>>>(pi,po,skel2); u64* t=pi; pi=po; po=t; }
  }

  // float soft_skel(prob, 10) = 11 d-terms: 5 packed double-steps + 1 packed single
  fskel2<true><<<2048,256,0,stream>>>(F1, F3, F2);
  fskel2<false><<<2048,256,0,stream>>>(F3, F1, F2);
  fskel2<false><<<2048,256,0,stream>>>(F1, F3, F2);
  fskel2<false><<<2048,256,0,stream>>>(F3, F1, F2);
  fskel2<false><<<2048,256,0,stream>>>(F1, F3, F2);
  fskel1<<<2048,256,0,stream>>>(F3, F2);

  const int GE = (2*NTOT)/256;
  edt_px<<<GE,256,0,stream>>>(ybits, hbits, dA);
  edt_py<<<GE,256,0,stream>>>(dA, dB);
  edt_pz_part<<<GE,256,0,stream>>>(dB, dA, skel2, hbits, pmaxv, pminv);
  rmm2<<<1,256,0,stream>>>(pmaxv, pminv, mm);

  k_tail<<<PC1,256,0,stream>>>(net, F4, F2, ybits, hbits, skel2, dA, mm, part1);
  k_reduce_mid<<<14,256,0,stream>>>(part0, part1, tot);
  k_fin<<<1,64,0,stream>>>(tot, out);
}